// Round 8
// baseline (348.621 us; speedup 1.0000x reference)
//
#include <hip/hip_runtime.h>

#define NF 64        // feature width
#define BC 32        // edge chunks
#define RANGE 8192   // nodes per hist range; key space per block = 2*RANGE
#define KLDS (RANGE * 2)

// f32 -> bf16 round-to-nearest-even
__device__ __forceinline__ unsigned short f2bf(float f) {
  unsigned int u = __float_as_uint(f);
  return (unsigned short)((u + 0x7fffu + ((u >> 16) & 1u)) >> 16);
}

// ---------------------------------------------------------------------------
// Per-(range,chunk) LDS histograms. kind 0: key = 2*dst + (src>=half) ->
// Gin[b][key] (ushort). kind 1: src -> Gout[b][node] (deg_out path).
__global__ __launch_bounds__(256) void hist_kernel(
    const int* __restrict__ src, const int* __restrict__ dst,
    unsigned short* __restrict__ Gout, unsigned short* __restrict__ Gin,
    int n, int nE, int R, int half) {
  __shared__ int cnt[KLDS];
  const int t = threadIdx.x;
  const int kind = blockIdx.x / (R * BC);
  const int rb = blockIdx.x % (R * BC);
  const int r = rb / BC, b = rb % BC;
  const int r0 = r * RANGE;
  const int chunk = (nE + BC - 1) / BC;
  const int lo = b * chunk, hi = min(lo + chunk, nE);
  if (kind == 0) {
    for (int i = t; i < KLDS; i += 256) cnt[i] = 0;
    __syncthreads();
    for (int e = lo + t; e < hi; e += 256) {
      int d = dst[e];
      unsigned int k = (unsigned int)(d - r0);
      if (k < (unsigned int)RANGE)
        atomicAdd(&cnt[k * 2 + (src[e] >= half)], 1);
    }
    __syncthreads();
    const int m2 = 2 * n;
    for (int i = t; i < KLDS; i += 256) {
      int key = r0 * 2 + i;
      if (key < m2) Gin[(size_t)b * m2 + key] = (unsigned short)cnt[i];
    }
  } else {
    for (int i = t; i < RANGE; i += 256) cnt[i] = 0;
    __syncthreads();
    for (int e = lo + t; e < hi; e += 256) {
      unsigned int k = (unsigned int)(src[e] - r0);
      if (k < (unsigned int)RANGE) atomicAdd(&cnt[k], 1);
    }
    __syncthreads();
    for (int i = t; i < RANGE; i += 256) {
      int nidx = r0 + i;
      if (nidx < n) Gout[(size_t)b * n + nidx] = (unsigned short)cnt[i];
    }
  }
}

// ---------------------------------------------------------------------------
// Per node: exclusive scan of Gin's two keys down the chunks (in place ->
// per-chunk bases, packed ushort2-as-uint), key degrees -> kdeg, and the
// deg^{-1/2} factors (deg_in = sum of both keys, deg_out = sum over Gout).
__global__ __launch_bounds__(256) void colscan_kernel(
    unsigned short* __restrict__ Gin, const unsigned short* __restrict__ Gout,
    int* __restrict__ kdeg, float* __restrict__ so, float* __restrict__ si,
    int n) {
  int i = blockIdx.x * 256 + threadIdx.x;
  if (i >= n) return;
  const size_t m2 = 2 * (size_t)n;
  int base0 = 0, base1 = 0;
  #pragma unroll 8
  for (int b = 0; b < BC; ++b) {
    unsigned int* p = (unsigned int*)(Gin + b * m2 + 2 * i);
    unsigned int cw = *p;
    *p = (base0 & 0xffffu) | ((unsigned int)base1 << 16);
    base0 += cw & 0xffffu;
    base1 += cw >> 16;
  }
  kdeg[2 * i] = base0;
  kdeg[2 * i + 1] = base1;
  int dout = 0;
  #pragma unroll 8
  for (int b = 0; b < BC; ++b) dout += Gout[(size_t)b * n + i];
  int din = base0 + base1;
  si[i] = din > 0 ? rsqrtf((float)din) : 0.f;
  so[i] = dout > 0 ? rsqrtf((float)dout) : 0.f;
}

// ---------------------------------------------------------------------------
// Exclusive scan over the 2N key space: scan1 (per-block) + scan3 (finalize).
__global__ __launch_bounds__(256) void scan1_kernel(
    const int* __restrict__ deg, int* __restrict__ lscan,
    int* __restrict__ bsum, int m) {
  __shared__ int s[256];
  int tid = threadIdx.x;
  int i = blockIdx.x * 256 + tid;
  int v = (i < m) ? deg[i] : 0;
  s[tid] = v;
  __syncthreads();
  #pragma unroll
  for (int off = 1; off < 256; off <<= 1) {
    int t2 = (tid >= off) ? s[tid - off] : 0;
    __syncthreads();
    s[tid] += t2;
    __syncthreads();
  }
  if (i < m) lscan[i] = s[tid] - v;
  if (tid == 255) bsum[blockIdx.x] = s[255];
}

__global__ __launch_bounds__(256) void scan3_kernel(
    const int* __restrict__ lscan, const int* __restrict__ bsum,
    int* __restrict__ rs2, int m, int nE) {
  __shared__ int red[256];
  const int tid = threadIdx.x;
  const int b = blockIdx.x;
  int partial = 0;
  for (int j = tid; j < b; j += 256) partial += bsum[j];
  red[tid] = partial;
  __syncthreads();
  #pragma unroll
  for (int s = 128; s > 0; s >>= 1) {
    if (tid < s) red[tid] += red[tid + s];
    __syncthreads();
  }
  const int off = red[0];
  const int i = b * 256 + tid;
  if (b == 0 && tid == 0) rs2[m] = nE;
  if (i < m) rs2[i] = lscan[i] + off;
}

// Atomic-free placement over the (dst, src-half) key space.
__global__ __launch_bounds__(256) void place_kernel(
    const int* __restrict__ src, const int* __restrict__ dst,
    const unsigned short* __restrict__ Gin, const int* __restrict__ rs2,
    unsigned short* __restrict__ sorted, int n, int nE, int half) {
  __shared__ int cnt[KLDS];
  const int rb = blockIdx.x;
  const int r = rb / BC, b = rb % BC;
  const int r0 = r * RANGE;
  for (int i = threadIdx.x; i < KLDS; i += 256) cnt[i] = 0;
  __syncthreads();
  const int chunk = (nE + BC - 1) / BC;
  const int lo = b * chunk, hi = min(lo + chunk, nE);
  const size_t m2 = 2 * (size_t)n;
  for (int e = lo + threadIdx.x; e < hi; e += 256) {
    int d = dst[e];
    unsigned int k = (unsigned int)(d - r0);
    if (k < (unsigned int)RANGE) {
      int s = src[e];
      int rk = (s >= half);
      int rank = atomicAdd(&cnt[k * 2 + rk], 1);
      int key = 2 * d + rk;
      int pos = rs2[key] + (int)Gin[(size_t)b * m2 + key] + rank;
      sorted[pos] = (unsigned short)s;
    }
  }
}

// ---------------------------------------------------------------------------
// Register-blocked GEMM (layer 1): h1 = bf16((x*so) @ W1).
__global__ __launch_bounds__(256) void gemm1_kernel(
    const float* __restrict__ A, const float* __restrict__ so,
    const float* __restrict__ W, unsigned short* __restrict__ H, int n) {
  __shared__ float Wl[NF * NF];
  __shared__ float Xl[NF * 68];
  const int t = threadIdx.x;

  #pragma unroll
  for (int i = 0; i < 16; ++i) Wl[t + 256 * i] = W[t + 256 * i];

  const int row0 = blockIdx.x * 64;
  #pragma unroll
  for (int i = 0; i < 16; ++i) {
    int idx = t + 256 * i;
    int r = idx >> 6;
    int c = idx & 63;
    int gr = row0 + r;
    float v = 0.f;
    if (gr < n) v = A[(size_t)gr * NF + c] * so[gr];
    Xl[r * 68 + c] = v;
  }
  __syncthreads();

  const int tx = t & 15;
  const int ty = t >> 4;
  float4 acc0 = {0, 0, 0, 0}, acc1 = {0, 0, 0, 0};
  float4 acc2 = {0, 0, 0, 0}, acc3 = {0, 0, 0, 0};

  #pragma unroll
  for (int k4 = 0; k4 < 16; ++k4) {
    const float4 a0 = *(const float4*)&Xl[(ty * 4 + 0) * 68 + k4 * 4];
    const float4 a1 = *(const float4*)&Xl[(ty * 4 + 1) * 68 + k4 * 4];
    const float4 a2 = *(const float4*)&Xl[(ty * 4 + 2) * 68 + k4 * 4];
    const float4 a3 = *(const float4*)&Xl[(ty * 4 + 3) * 68 + k4 * 4];
    const float4 b0 = *(const float4*)&Wl[(k4 * 4 + 0) * NF + tx * 4];
    const float4 b1 = *(const float4*)&Wl[(k4 * 4 + 1) * NF + tx * 4];
    const float4 b2 = *(const float4*)&Wl[(k4 * 4 + 2) * NF + tx * 4];
    const float4 b3 = *(const float4*)&Wl[(k4 * 4 + 3) * NF + tx * 4];

#define FMA4(ACC, AV, BV)                         \
    ACC.x = fmaf(AV, BV.x, ACC.x);                \
    ACC.y = fmaf(AV, BV.y, ACC.y);                \
    ACC.z = fmaf(AV, BV.z, ACC.z);                \
    ACC.w = fmaf(AV, BV.w, ACC.w);
    FMA4(acc0, a0.x, b0) FMA4(acc0, a0.y, b1) FMA4(acc0, a0.z, b2) FMA4(acc0, a0.w, b3)
    FMA4(acc1, a1.x, b0) FMA4(acc1, a1.y, b1) FMA4(acc1, a1.z, b2) FMA4(acc1, a1.w, b3)
    FMA4(acc2, a2.x, b0) FMA4(acc2, a2.y, b1) FMA4(acc2, a2.z, b2) FMA4(acc2, a2.w, b3)
    FMA4(acc3, a3.x, b0) FMA4(acc3, a3.y, b1) FMA4(acc3, a3.z, b2) FMA4(acc3, a3.w, b3)
#undef FMA4
  }

  const int col = tx * 4;
  #pragma unroll
  for (int i = 0; i < 4; ++i) {
    int gr = row0 + ty * 4 + i;
    if (gr >= n) continue;
    float4 v = (i == 0) ? acc0 : (i == 1) ? acc1 : (i == 2) ? acc2 : acc3;
    ushort4 o;
    o.x = f2bf(v.x); o.y = f2bf(v.y); o.z = f2bf(v.z); o.w = f2bf(v.w);
    *(ushort4*)&H[(size_t)gr * NF + col] = o;
  }
}

// ---------------------------------------------------------------------------
// Gather/accumulate (one wave per node, bf16 rows, 8 rows per instruction;
// butterfly leaves the full row sum in every lane: features (lane&7)*8..+7).
__device__ __forceinline__ void gather_sum(
    const unsigned short* __restrict__ H, const unsigned short* __restrict__ srcs,
    int beg, int end, int g, int c, float* acc) {
  const float4* Hv = (const float4*)H;
  int e = beg;
  for (; e + 16 <= end; e += 16) {
    int ia = srcs[e + g];
    int ib = srcs[e + 8 + g];
    float4 va = Hv[(size_t)ia * 8 + c];
    float4 vb = Hv[(size_t)ib * 8 + c];
    const unsigned int* pa = (const unsigned int*)&va;
    const unsigned int* pb = (const unsigned int*)&vb;
    #pragma unroll
    for (int k = 0; k < 4; ++k) {
      acc[2 * k]     += __uint_as_float(pa[k] << 16) + __uint_as_float(pb[k] << 16);
      acc[2 * k + 1] += __uint_as_float(pa[k] & 0xffff0000u) + __uint_as_float(pb[k] & 0xffff0000u);
    }
  }
  if (e + 8 <= end) {
    int ia = srcs[e + g];
    float4 va = Hv[(size_t)ia * 8 + c];
    const unsigned int* pa = (const unsigned int*)&va;
    #pragma unroll
    for (int k = 0; k < 4; ++k) {
      acc[2 * k]     += __uint_as_float(pa[k] << 16);
      acc[2 * k + 1] += __uint_as_float(pa[k] & 0xffff0000u);
    }
    e += 8;
  }
  if (e < end) {
    int idx = (e + g < end) ? (e + g) : (end - 1);
    float m = (e + g < end) ? 1.f : 0.f;
    int ia = srcs[idx];
    float4 va = Hv[(size_t)ia * 8 + c];
    const unsigned int* pa = (const unsigned int*)&va;
    #pragma unroll
    for (int k = 0; k < 4; ++k) {
      acc[2 * k]     += m * __uint_as_float(pa[k] << 16);
      acc[2 * k + 1] += m * __uint_as_float(pa[k] & 0xffff0000u);
    }
  }
  #pragma unroll
  for (int d = 8; d <= 32; d <<= 1) {
    #pragma unroll
    for (int k = 0; k < 8; ++k) acc[k] += __shfl_xor(acc[k], d);
  }
}

// Layer-1 aggregation in two src-slice passes (each slice's table half fits a
// 4 MiB XCD L2). PASS 0: partial sums -> P (f32). PASS 1: gather slice 1,
// add P, epilogue relu(...)*so, then the fused layer-2 matvec -> h2 bf16.
template <int PASS>
__global__ __launch_bounds__(256) void aggA_kernel(
    const unsigned short* __restrict__ H1, const int* __restrict__ rs2,
    const unsigned short* __restrict__ srcs, const float* __restrict__ si,
    const float* __restrict__ so, const float* __restrict__ b1,
    const float* __restrict__ W2, float* __restrict__ P,
    unsigned short* __restrict__ H2, int n) {
  __shared__ float Wl[PASS ? NF * NF : 1];
  const int t = threadIdx.x;
  if (PASS) {
    #pragma unroll
    for (int i = 0; i < 16; ++i) Wl[t + 256 * i] = W2[t + 256 * i];
    __syncthreads();
  }
  int node = blockIdx.x * 4 + (t >> 6);
  if (node >= n) return;
  const int lane = t & 63;
  const int g = lane >> 3;
  const int c = lane & 7;
  const int beg = rs2[2 * node + PASS];
  const int end = rs2[2 * node + PASS + 1];

  float acc[8] = {0, 0, 0, 0, 0, 0, 0, 0};
  gather_sum(H1, srcs, beg, end, g, c, acc);

  if (PASS == 0) {
    if (g == 0) {
      *(float4*)&P[(size_t)node * NF + c * 8]     = make_float4(acc[0], acc[1], acc[2], acc[3]);
      *(float4*)&P[(size_t)node * NF + c * 8 + 4] = make_float4(acc[4], acc[5], acc[6], acc[7]);
    }
  } else {
    const float4 p0 = *(const float4*)&P[(size_t)node * NF + c * 8];
    const float4 p1 = *(const float4*)&P[(size_t)node * NF + c * 8 + 4];
    acc[0] += p0.x; acc[1] += p0.y; acc[2] += p0.z; acc[3] += p0.w;
    acc[4] += p1.x; acc[5] += p1.y; acc[6] += p1.z; acc[7] += p1.w;
    const float sin = si[node];
    const float son = so[node];
    #pragma unroll
    for (int k = 0; k < 8; ++k)
      acc[k] = fmaxf(fmaf(acc[k], sin, b1[c * 8 + k]), 0.f) * son;
    float o = 0.f;
    #pragma unroll
    for (int k = 0; k < NF; ++k) {
      float tk = __shfl(acc[k & 7], k >> 3);
      o = fmaf(tk, Wl[k * NF + lane], o);
    }
    H2[(size_t)node * NF + lane] = f2bf(o);
  }
}

// Layer-2 aggregation, same two-pass structure. PASS 1 adds P, *si + b2 -> out.
template <int PASS>
__global__ __launch_bounds__(256) void aggB_kernel(
    const unsigned short* __restrict__ H2, const int* __restrict__ rs2,
    const unsigned short* __restrict__ srcs, const float* __restrict__ si,
    const float* __restrict__ b2, float* __restrict__ P,
    float* __restrict__ out, int n) {
  int node = blockIdx.x * 4 + (threadIdx.x >> 6);
  if (node >= n) return;
  const int lane = threadIdx.x & 63;
  const int g = lane >> 3;
  const int c = lane & 7;
  const int beg = rs2[2 * node + PASS];
  const int end = rs2[2 * node + PASS + 1];

  float acc[8] = {0, 0, 0, 0, 0, 0, 0, 0};
  gather_sum(H2, srcs, beg, end, g, c, acc);

  if (g == 0) {
    if (PASS == 0) {
      *(float4*)&P[(size_t)node * NF + c * 8]     = make_float4(acc[0], acc[1], acc[2], acc[3]);
      *(float4*)&P[(size_t)node * NF + c * 8 + 4] = make_float4(acc[4], acc[5], acc[6], acc[7]);
    } else {
      const float4 p0 = *(const float4*)&P[(size_t)node * NF + c * 8];
      const float4 p1 = *(const float4*)&P[(size_t)node * NF + c * 8 + 4];
      const float pp[8] = {p0.x, p0.y, p0.z, p0.w, p1.x, p1.y, p1.z, p1.w};
      const float sin = si[node];
      const float4 b4a = *(const float4*)&b2[c * 8];
      const float4 b4b = *(const float4*)&b2[c * 8 + 4];
      const float bb[8] = {b4a.x, b4a.y, b4a.z, b4a.w, b4b.x, b4b.y, b4b.z, b4b.w};
      float r[8];
      #pragma unroll
      for (int k = 0; k < 8; ++k) r[k] = fmaf(acc[k] + pp[k], sin, bb[k]);
      *(float4*)&out[(size_t)node * NF + c * 8]     = make_float4(r[0], r[1], r[2], r[3]);
      *(float4*)&out[(size_t)node * NF + c * 8 + 4] = make_float4(r[4], r[5], r[6], r[7]);
    }
  }
}

// ---------------------------------------------------------------------------
extern "C" void kernel_launch(void* const* d_in, const int* in_sizes, int n_in,
                              void* d_out, int out_size, void* d_ws, size_t ws_size,
                              hipStream_t stream) {
  const float* x  = (const float*)d_in[0];
  const float* W1 = (const float*)d_in[1];
  const float* b1 = (const float*)d_in[2];
  const float* W2 = (const float*)d_in[3];
  const float* b2 = (const float*)d_in[4];
  const int* src  = (const int*)d_in[5];
  const int* dst  = (const int*)d_in[6];
  float* out = (float*)d_out;

  const int N = in_sizes[0] / NF;   // 50000 (< 65536 for ushort ids)
  const int E = in_sizes[5];        // 800000
  const int HALF = N / 2;           // src-slice boundary (3.2 MB bf16 table half)
  const int M2 = 2 * N;             // key space (dst, src-half)
  const int NB  = (N + 255) / 256;
  const int NB2 = (M2 + 255) / 256;
  const int R = (N + RANGE - 1) / RANGE;  // 7

  // Workspace (~28 MB). Sort-prep arrays alias P (all dead before aggA0).
  char* ws = (char*)d_ws;
  size_t p = 0;
  auto alloc = [&](size_t bytes) -> void* {
    void* r = ws + p;
    p = (p + bytes + 255) & ~(size_t)255;
    return r;
  };
  float* P = (float*)alloc((size_t)N * NF * 4);   // 12.8 MB partial sums
  {
    char* q = (char*)P;
    (void)q;
  }
  unsigned short* Gout   = (unsigned short*)P;                       // 3.2 MB
  unsigned short* Gin    = (unsigned short*)((char*)Gout + (size_t)BC * N * 2);  // 6.4 MB
  int* kdeg   = (int*)((char*)Gin + (size_t)BC * M2 * 2);            // 0.4 MB
  int* lscan2 = kdeg + M2;                                           // 0.4 MB
  int* bsum2  = lscan2 + M2;                                         // ~1.6 KB
  float* so        = (float*)alloc((size_t)N * 4);
  float* si        = (float*)alloc((size_t)N * 4);
  int*   rs2       = (int*)  alloc((size_t)(M2 + 1) * 4);
  unsigned short* sorted_u16 = (unsigned short*)alloc((size_t)E * 2);
  unsigned short* h1 = (unsigned short*)alloc((size_t)N * NF * 2);   // bf16
  unsigned short* h2 = (unsigned short*)alloc((size_t)N * NF * 2);   // bf16

  // 1. histograms over (dst, src-half) keys + src (deg_out)
  hist_kernel<<<2 * R * BC, 256, 0, stream>>>(src, dst, Gout, Gin, N, E, R, HALF);

  // 2. per-key chunk bases + key degrees + si/so
  colscan_kernel<<<NB, 256, 0, stream>>>(Gin, Gout, kdeg, so, si, N);

  // 3. exclusive scan over 2N keys -> rs2
  scan1_kernel<<<NB2, 256, 0, stream>>>(kdeg, lscan2, bsum2, M2);
  scan3_kernel<<<NB2, 256, 0, stream>>>(lscan2, bsum2, rs2, M2, E);

  // 4. atomic-free placement (sorted by (dst, src-half))
  place_kernel<<<R * BC, 256, 0, stream>>>(src, dst, Gin, rs2, sorted_u16, N, E, HALF);

  const int ggrid = (N + 63) / 64;
  const int agrid = (N + 3) / 4;

  // 5. layer 1: h1 = bf16((x*so) @ W1)
  gemm1_kernel<<<ggrid, 256, 0, stream>>>(x, so, W1, h1, N);

  // 6. layer-1 aggregation in two L2-resident slices + fused layer-2 matvec
  aggA_kernel<0><<<agrid, 256, 0, stream>>>(h1, rs2, sorted_u16, si, so, b1, W2, P, h2, N);
  aggA_kernel<1><<<agrid, 256, 0, stream>>>(h1, rs2, sorted_u16, si, so, b1, W2, P, h2, N);

  // 7. layer-2 aggregation, same structure: out = segsum(h2)*si + b2
  aggB_kernel<0><<<agrid, 256, 0, stream>>>(h2, rs2, sorted_u16, si, b2, P, out, N);
  aggB_kernel<1><<<agrid, 256, 0, stream>>>(h2, rs2, sorted_u16, si, b2, P, out, N);
}

// Round 9
// 267.915 us; speedup vs baseline: 1.3012x; 1.3012x over previous
//
#include <hip/hip_runtime.h>

#define NF 64        // feature width
#define BC 32        // edge chunks
#define RANGE 8192   // node-range for LDS histograms (32 KB int counters)

// f32 -> bf16 round-to-nearest-even
__device__ __forceinline__ unsigned short f2bf(float f) {
  unsigned int u = __float_as_uint(f);
  return (unsigned short)((u + 0x7fffu + ((u >> 16) & 1u)) >> 16);
}

// ---------------------------------------------------------------------------
// Per-(range,chunk) LDS histograms. kind 0: dst -> Gin[b][node];
// kind 1: src -> Gout[b][node] (ushort counts).
__global__ __launch_bounds__(256) void hist_kernel(
    const int* __restrict__ src, const int* __restrict__ dst,
    unsigned short* __restrict__ Gout, unsigned short* __restrict__ Gin,
    int n, int nE, int R) {
  __shared__ int cnt[RANGE];
  const int rb = blockIdx.x % (R * BC);
  const int kind = blockIdx.x / (R * BC);
  const int r = rb / BC, b = rb % BC;
  const int r0 = r * RANGE;
  for (int i = threadIdx.x; i < RANGE; i += 256) cnt[i] = 0;
  __syncthreads();
  const int* keys = kind ? src : dst;
  const int chunk = (nE + BC - 1) / BC;
  const int lo = b * chunk, hi = min(lo + chunk, nE);
  for (int e = lo + threadIdx.x; e < hi; e += 256) {
    unsigned int k = (unsigned int)(keys[e] - r0);
    if (k < (unsigned int)RANGE) atomicAdd(&cnt[k], 1);
  }
  __syncthreads();
  unsigned short* G = kind ? Gout : Gin;
  for (int i = threadIdx.x; i < RANGE; i += 256) {
    int nidx = r0 + i;
    if (nidx < n) G[(size_t)b * n + nidx] = (unsigned short)cnt[i];
  }
}

// ---------------------------------------------------------------------------
// Fused colscan + scan1: per node, exclusive scan of Gin down the chunks
// (in place -> per-chunk bases) -> deg_in; sum Gout -> deg_out; then
// block-scan deg_in -> lscan + bsum.
__global__ __launch_bounds__(256) void colscan_scan1_kernel(
    unsigned short* __restrict__ Gin, const unsigned short* __restrict__ Gout,
    int* __restrict__ deg_in, int* __restrict__ deg_out,
    int* __restrict__ lscan, int* __restrict__ bsum, int n) {
  __shared__ int s[256];
  const int tid = threadIdx.x;
  const int i = blockIdx.x * 256 + tid;
  int di = 0;
  if (i < n) {
    int base = 0;
    #pragma unroll 8
    for (int b = 0; b < BC; ++b) {
      int c = Gin[(size_t)b * n + i];
      Gin[(size_t)b * n + i] = (unsigned short)base;
      base += c;
    }
    di = base;
    int dsum = 0;
    #pragma unroll 8
    for (int b = 0; b < BC; ++b) dsum += Gout[(size_t)b * n + i];
    deg_in[i] = di;
    deg_out[i] = dsum;
  }
  s[tid] = di;
  __syncthreads();
  #pragma unroll
  for (int off = 1; off < 256; off <<= 1) {
    int t2 = (tid >= off) ? s[tid - off] : 0;
    __syncthreads();
    s[tid] += t2;
    __syncthreads();
  }
  if (i < n) lscan[i] = s[tid] - di;
  if (tid == 255) bsum[blockIdx.x] = s[255];
}

// scan3: block b reduces bsum[0..b), finalizes row_start + deg^{-1/2}.
__global__ __launch_bounds__(256) void scan3_kernel(
    const int* __restrict__ lscan, const int* __restrict__ bsum,
    const int* __restrict__ deg_out, const int* __restrict__ deg_in,
    int* __restrict__ row_start, float* __restrict__ so, float* __restrict__ si,
    int n, int nE) {
  __shared__ int red[256];
  const int tid = threadIdx.x;
  const int b = blockIdx.x;
  red[tid] = (tid < b) ? bsum[tid] : 0;
  __syncthreads();
  #pragma unroll
  for (int s = 128; s > 0; s >>= 1) {
    if (tid < s) red[tid] += red[tid + s];
    __syncthreads();
  }
  const int off = red[0];
  const int i = b * 256 + tid;
  if (b == 0 && tid == 0) row_start[n] = nE;
  if (i < n) {
    row_start[i] = lscan[i] + off;
    int dO = deg_out[i];
    int dI = deg_in[i];
    so[i] = dO > 0 ? rsqrtf((float)dO) : 0.f;
    si[i] = dI > 0 ? rsqrtf((float)dI) : 0.f;
  }
}

// Atomic-free placement (standalone, full occupancy).
__global__ __launch_bounds__(256) void place_kernel(
    const int* __restrict__ src, const int* __restrict__ dst,
    const unsigned short* __restrict__ Gin, const int* __restrict__ row_start,
    unsigned short* __restrict__ sorted, int n, int nE) {
  __shared__ int cnt[RANGE];
  const int rb = blockIdx.x;
  const int r = rb / BC, b = rb % BC;
  const int r0 = r * RANGE;
  for (int i = threadIdx.x; i < RANGE; i += 256) cnt[i] = 0;
  __syncthreads();
  const int chunk = (nE + BC - 1) / BC;
  const int lo = b * chunk, hi = min(lo + chunk, nE);
  for (int e = lo + threadIdx.x; e < hi; e += 256) {
    int d = dst[e];
    unsigned int k = (unsigned int)(d - r0);
    if (k < (unsigned int)RANGE) {
      int rank = atomicAdd(&cnt[k], 1);
      int pos = row_start[d] + (int)Gin[(size_t)b * n + d] + rank;
      sorted[pos] = (unsigned short)src[e];
    }
  }
}

// ---------------------------------------------------------------------------
// Shared 64x64 register-blocked GEMM inner loop on staged LDS tiles.
__device__ __forceinline__ void gemm_core(
    const float* __restrict__ Wl, const float* __restrict__ Xl,
    unsigned short* __restrict__ H, int row0, int n, int t) {
  const int tx = t & 15;
  const int ty = t >> 4;
  float4 acc0 = {0, 0, 0, 0}, acc1 = {0, 0, 0, 0};
  float4 acc2 = {0, 0, 0, 0}, acc3 = {0, 0, 0, 0};

  #pragma unroll
  for (int k4 = 0; k4 < 16; ++k4) {
    const float4 a0 = *(const float4*)&Xl[(ty * 4 + 0) * 68 + k4 * 4];
    const float4 a1 = *(const float4*)&Xl[(ty * 4 + 1) * 68 + k4 * 4];
    const float4 a2 = *(const float4*)&Xl[(ty * 4 + 2) * 68 + k4 * 4];
    const float4 a3 = *(const float4*)&Xl[(ty * 4 + 3) * 68 + k4 * 4];
    const float4 b0 = *(const float4*)&Wl[(k4 * 4 + 0) * NF + tx * 4];
    const float4 b1 = *(const float4*)&Wl[(k4 * 4 + 1) * NF + tx * 4];
    const float4 b2 = *(const float4*)&Wl[(k4 * 4 + 2) * NF + tx * 4];
    const float4 b3 = *(const float4*)&Wl[(k4 * 4 + 3) * NF + tx * 4];

#define FMA4(ACC, AV, BV)                         \
    ACC.x = fmaf(AV, BV.x, ACC.x);                \
    ACC.y = fmaf(AV, BV.y, ACC.y);                \
    ACC.z = fmaf(AV, BV.z, ACC.z);                \
    ACC.w = fmaf(AV, BV.w, ACC.w);
    FMA4(acc0, a0.x, b0) FMA4(acc0, a0.y, b1) FMA4(acc0, a0.z, b2) FMA4(acc0, a0.w, b3)
    FMA4(acc1, a1.x, b0) FMA4(acc1, a1.y, b1) FMA4(acc1, a1.z, b2) FMA4(acc1, a1.w, b3)
    FMA4(acc2, a2.x, b0) FMA4(acc2, a2.y, b1) FMA4(acc2, a2.z, b2) FMA4(acc2, a2.w, b3)
    FMA4(acc3, a3.x, b0) FMA4(acc3, a3.y, b1) FMA4(acc3, a3.z, b2) FMA4(acc3, a3.w, b3)
#undef FMA4
  }

  const int col = tx * 4;
  #pragma unroll
  for (int i = 0; i < 4; ++i) {
    int gr = row0 + ty * 4 + i;
    if (gr >= n) continue;
    float4 v = (i == 0) ? acc0 : (i == 1) ? acc1 : (i == 2) ? acc2 : acc3;
    ushort4 o;
    o.x = f2bf(v.x); o.y = f2bf(v.y); o.z = f2bf(v.z); o.w = f2bf(v.w);
    *(ushort4*)&H[(size_t)gr * NF + col] = o;
  }
}

// Layer 1: h1 = bf16((x*so) @ W1), f32 input.
__global__ __launch_bounds__(256) void gemm1_kernel(
    const float* __restrict__ A, const float* __restrict__ so,
    const float* __restrict__ W, unsigned short* __restrict__ H, int n) {
  __shared__ float Wl[NF * NF];
  __shared__ float Xl[NF * 68];
  const int t = threadIdx.x;
  #pragma unroll
  for (int i = 0; i < 16; ++i) Wl[t + 256 * i] = W[t + 256 * i];
  const int row0 = blockIdx.x * 64;
  #pragma unroll
  for (int i = 0; i < 16; ++i) {
    int idx = t + 256 * i;
    int r = idx >> 6;
    int c = idx & 63;
    int gr = row0 + r;
    float v = 0.f;
    if (gr < n) v = A[(size_t)gr * NF + c] * so[gr];
    Xl[r * 68 + c] = v;
  }
  __syncthreads();
  gemm_core(Wl, Xl, H, row0, n, t);
}

// Layer 2: h2 = bf16(t @ W2), bf16 input (staged to f32 LDS).
__global__ __launch_bounds__(256) void gemm2_kernel(
    const unsigned short* __restrict__ Tb, const float* __restrict__ W,
    unsigned short* __restrict__ H, int n) {
  __shared__ float Wl[NF * NF];
  __shared__ float Xl[NF * 68];
  const int t = threadIdx.x;
  #pragma unroll
  for (int i = 0; i < 16; ++i) Wl[t + 256 * i] = W[t + 256 * i];
  const int row0 = blockIdx.x * 64;
  const unsigned int* Tw = (const unsigned int*)Tb;  // 2 bf16 per word, 32 words/row
  #pragma unroll
  for (int i = 0; i < 8; ++i) {
    int idx = t + 256 * i;        // [0, 2048) word index
    int r = idx >> 5;
    int w = idx & 31;
    int gr = row0 + r;
    unsigned int u = (gr < n) ? Tw[(size_t)gr * 32 + w] : 0u;
    Xl[r * 68 + 2 * w]     = __uint_as_float(u << 16);
    Xl[r * 68 + 2 * w + 1] = __uint_as_float(u & 0xffff0000u);
  }
  __syncthreads();
  gemm_core(Wl, Xl, H, row0, n, t);
}

// ---------------------------------------------------------------------------
// Gather/accumulate (one wave per node, bf16 rows = 128 B, 8 rows per VMEM
// instruction; butterfly leaves the full row sum in every lane:
// features (lane&7)*8 .. +7 in acc[0..7]).
__device__ __forceinline__ void gather_sum(
    const unsigned short* __restrict__ H, const unsigned short* __restrict__ srcs,
    int beg, int end, int g, int c, float* acc) {
  const float4* Hv = (const float4*)H;
  int e = beg;
  for (; e + 16 <= end; e += 16) {
    int ia = srcs[e + g];
    int ib = srcs[e + 8 + g];
    float4 va = Hv[(size_t)ia * 8 + c];
    float4 vb = Hv[(size_t)ib * 8 + c];
    const unsigned int* pa = (const unsigned int*)&va;
    const unsigned int* pb = (const unsigned int*)&vb;
    #pragma unroll
    for (int k = 0; k < 4; ++k) {
      acc[2 * k]     += __uint_as_float(pa[k] << 16) + __uint_as_float(pb[k] << 16);
      acc[2 * k + 1] += __uint_as_float(pa[k] & 0xffff0000u) + __uint_as_float(pb[k] & 0xffff0000u);
    }
  }
  if (e + 8 <= end) {
    int ia = srcs[e + g];
    float4 va = Hv[(size_t)ia * 8 + c];
    const unsigned int* pa = (const unsigned int*)&va;
    #pragma unroll
    for (int k = 0; k < 4; ++k) {
      acc[2 * k]     += __uint_as_float(pa[k] << 16);
      acc[2 * k + 1] += __uint_as_float(pa[k] & 0xffff0000u);
    }
    e += 8;
  }
  if (e < end) {
    int idx = (e + g < end) ? (e + g) : (end - 1);
    float m = (e + g < end) ? 1.f : 0.f;
    int ia = srcs[idx];
    float4 va = Hv[(size_t)ia * 8 + c];
    const unsigned int* pa = (const unsigned int*)&va;
    #pragma unroll
    for (int k = 0; k < 4; ++k) {
      acc[2 * k]     += m * __uint_as_float(pa[k] << 16);
      acc[2 * k + 1] += m * __uint_as_float(pa[k] & 0xffff0000u);
    }
  }
  #pragma unroll
  for (int d = 8; d <= 32; d <<= 1) {
    #pragma unroll
    for (int k = 0; k < 8; ++k) acc[k] += __shfl_xor(acc[k], d);
  }
}

// Layer-1 aggregation: t = bf16(relu(segsum(h1)*si + b1) * so).
// No matvec here (r6-r8's fused shfl-matvec was ~60us of LDS-pipe issue).
__global__ __launch_bounds__(256) void agg1_kernel(
    const unsigned short* __restrict__ H1, const int* __restrict__ row_start,
    const unsigned short* __restrict__ srcs, const float* __restrict__ si,
    const float* __restrict__ so, const float* __restrict__ b1,
    unsigned short* __restrict__ T, int n) {
  int node = blockIdx.x * 4 + (threadIdx.x >> 6);
  if (node >= n) return;
  const int lane = threadIdx.x & 63;
  const int g = lane >> 3;
  const int c = lane & 7;
  float acc[8] = {0, 0, 0, 0, 0, 0, 0, 0};
  gather_sum(H1, srcs, row_start[node], row_start[node + 1], g, c, acc);
  if (g == 0) {
    const float sin = si[node];
    const float son = so[node];
    ushort4 o0, o1;
    float v;
    v = fmaxf(fmaf(acc[0], sin, b1[c * 8 + 0]), 0.f) * son; o0.x = f2bf(v);
    v = fmaxf(fmaf(acc[1], sin, b1[c * 8 + 1]), 0.f) * son; o0.y = f2bf(v);
    v = fmaxf(fmaf(acc[2], sin, b1[c * 8 + 2]), 0.f) * son; o0.z = f2bf(v);
    v = fmaxf(fmaf(acc[3], sin, b1[c * 8 + 3]), 0.f) * son; o0.w = f2bf(v);
    v = fmaxf(fmaf(acc[4], sin, b1[c * 8 + 4]), 0.f) * son; o1.x = f2bf(v);
    v = fmaxf(fmaf(acc[5], sin, b1[c * 8 + 5]), 0.f) * son; o1.y = f2bf(v);
    v = fmaxf(fmaf(acc[6], sin, b1[c * 8 + 6]), 0.f) * son; o1.z = f2bf(v);
    v = fmaxf(fmaf(acc[7], sin, b1[c * 8 + 7]), 0.f) * son; o1.w = f2bf(v);
    *(ushort4*)&T[(size_t)node * NF + c * 8]     = o0;
    *(ushort4*)&T[(size_t)node * NF + c * 8 + 4] = o1;
  }
}

// Layer-2 aggregation: out = segsum(h2)*si + b2 (f32).
__global__ __launch_bounds__(256) void agg2_kernel(
    const unsigned short* __restrict__ H2, const int* __restrict__ row_start,
    const unsigned short* __restrict__ srcs, const float* __restrict__ si,
    const float* __restrict__ b2, float* __restrict__ out, int n) {
  int node = blockIdx.x * 4 + (threadIdx.x >> 6);
  if (node >= n) return;
  const int lane = threadIdx.x & 63;
  const int g = lane >> 3;
  const int c = lane & 7;
  float acc[8] = {0, 0, 0, 0, 0, 0, 0, 0};
  gather_sum(H2, srcs, row_start[node], row_start[node + 1], g, c, acc);
  if (g == 0) {
    const float sin = si[node];
    const float4 b4a = *(const float4*)&b2[c * 8];
    const float4 b4b = *(const float4*)&b2[c * 8 + 4];
    float4 r0, r1;
    r0.x = fmaf(acc[0], sin, b4a.x);
    r0.y = fmaf(acc[1], sin, b4a.y);
    r0.z = fmaf(acc[2], sin, b4a.z);
    r0.w = fmaf(acc[3], sin, b4a.w);
    r1.x = fmaf(acc[4], sin, b4b.x);
    r1.y = fmaf(acc[5], sin, b4b.y);
    r1.z = fmaf(acc[6], sin, b4b.z);
    r1.w = fmaf(acc[7], sin, b4b.w);
    *(float4*)&out[(size_t)node * NF + c * 8]     = r0;
    *(float4*)&out[(size_t)node * NF + c * 8 + 4] = r1;
  }
}

// ---------------------------------------------------------------------------
extern "C" void kernel_launch(void* const* d_in, const int* in_sizes, int n_in,
                              void* d_out, int out_size, void* d_ws, size_t ws_size,
                              hipStream_t stream) {
  const float* x  = (const float*)d_in[0];
  const float* W1 = (const float*)d_in[1];
  const float* b1 = (const float*)d_in[2];
  const float* W2 = (const float*)d_in[3];
  const float* b2 = (const float*)d_in[4];
  const int* src  = (const int*)d_in[5];
  const int* dst  = (const int*)d_in[6];
  float* out = (float*)d_out;

  const int N = in_sizes[0] / NF;   // 50000 (< 65536 for ushort ids)
  const int E = in_sizes[5];        // 800000
  const int NB = (N + 255) / 256;   // 196 <= 256
  const int R  = (N + RANGE - 1) / RANGE;  // 7

  // Workspace (~23 MB), no memsets needed (everything written before read).
  char* ws = (char*)d_ws;
  size_t p = 0;
  auto alloc = [&](size_t bytes) -> void* {
    void* r = ws + p;
    p = (p + bytes + 255) & ~(size_t)255;
    return r;
  };
  int*   deg_out_i  = (int*)  alloc((size_t)N * 4);
  int*   deg_in_i   = (int*)  alloc((size_t)N * 4);
  float* so         = (float*)alloc((size_t)N * 4);
  float* si         = (float*)alloc((size_t)N * 4);
  int*   row_start  = (int*)  alloc((size_t)(N + 1) * 4);
  int*   bsum       = (int*)  alloc((size_t)NB * 4);
  int*   lscan      = (int*)  alloc((size_t)N * 4);
  unsigned short* sorted_u16 = (unsigned short*)alloc((size_t)E * 2);
  unsigned short* h1   = (unsigned short*)alloc((size_t)N * NF * 2);  // bf16; reused as h2
  unsigned short* tb   = (unsigned short*)alloc((size_t)N * NF * 2);  // bf16 t
  unsigned short* G_in  = (unsigned short*)alloc((size_t)BC * N * 2); // 3.2 MB
  unsigned short* G_out = (unsigned short*)alloc((size_t)BC * N * 2); // 3.2 MB
  unsigned short* h2 = h1;  // h1 dead once agg1 completes; gemm2 runs after

  // 1. per-(range,chunk) histograms for both endpoints
  hist_kernel<<<2 * R * BC, 256, 0, stream>>>(src, dst, G_out, G_in, N, E, R);

  // 2. fused column-scan (per-chunk bases + degrees) + block scan
  colscan_scan1_kernel<<<NB, 256, 0, stream>>>(G_in, G_out, deg_in_i, deg_out_i,
                                               lscan, bsum, N);

  // 3. row_start + so/si
  scan3_kernel<<<NB, 256, 0, stream>>>(lscan, bsum, deg_out_i, deg_in_i,
                                       row_start, so, si, N, E);

  // 4. atomic-free placement
  place_kernel<<<R * BC, 256, 0, stream>>>(src, dst, G_in, row_start,
                                           sorted_u16, N, E);

  const int ggrid = (N + 63) / 64;
  const int agrid = (N + 3) / 4;

  // 5. layer 1: h1 = bf16((x*so) @ W1)
  gemm1_kernel<<<ggrid, 256, 0, stream>>>(x, so, W1, h1, N);

  // 6. t = bf16(relu(segsum(h1)*si + b1) * so)
  agg1_kernel<<<agrid, 256, 0, stream>>>(h1, row_start, sorted_u16, si, so, b1, tb, N);

  // 7. h2 = bf16(t @ W2)   (tiled GEMM, not shfl-matvec)
  gemm2_kernel<<<ggrid, 256, 0, stream>>>(tb, W2, h2, N);

  // 8. out = segsum(h2)*si + b2
  agg2_kernel<<<agrid, 256, 0, stream>>>(h2, row_start, sorted_u16, si, b2, out, N);
}

// Round 10
// 216.709 us; speedup vs baseline: 1.6087x; 1.2363x over previous
//
#include <hip/hip_runtime.h>

#define NF 64        // feature width
#define BC 32        // edge chunks
#define RANGE 8192   // node-range for LDS histograms (32 KB int counters)

typedef __attribute__((ext_vector_type(8))) short short8;    // 8 bf16 (4 VGPRs)
typedef __attribute__((ext_vector_type(4))) float floatx4;   // MFMA accumulator

// f32 -> bf16 round-to-nearest-even
__device__ __forceinline__ unsigned short f2bf(float f) {
  unsigned int u = __float_as_uint(f);
  return (unsigned short)((u + 0x7fffu + ((u >> 16) & 1u)) >> 16);
}

// ---------------------------------------------------------------------------
// Per-(range,chunk) LDS histograms. kind 0: dst -> Gin[b][node];
// kind 1: src -> Gout[b][node] (ushort counts).
__global__ __launch_bounds__(256) void hist_kernel(
    const int* __restrict__ src, const int* __restrict__ dst,
    unsigned short* __restrict__ Gout, unsigned short* __restrict__ Gin,
    int n, int nE, int R) {
  __shared__ int cnt[RANGE];
  const int rb = blockIdx.x % (R * BC);
  const int kind = blockIdx.x / (R * BC);
  const int r = rb / BC, b = rb % BC;
  const int r0 = r * RANGE;
  for (int i = threadIdx.x; i < RANGE; i += 256) cnt[i] = 0;
  __syncthreads();
  const int* keys = kind ? src : dst;
  const int chunk = (nE + BC - 1) / BC;
  const int lo = b * chunk, hi = min(lo + chunk, nE);
  for (int e = lo + threadIdx.x; e < hi; e += 256) {
    unsigned int k = (unsigned int)(keys[e] - r0);
    if (k < (unsigned int)RANGE) atomicAdd(&cnt[k], 1);
  }
  __syncthreads();
  unsigned short* G = kind ? Gout : Gin;
  for (int i = threadIdx.x; i < RANGE; i += 256) {
    int nidx = r0 + i;
    if (nidx < n) G[(size_t)b * n + nidx] = (unsigned short)cnt[i];
  }
}

// ---------------------------------------------------------------------------
// Fused colscan + scan1: per node, exclusive scan of Gin down the chunks
// (in place -> per-chunk bases) -> deg_in; sum Gout -> deg_out; then
// block-scan deg_in -> lscan + bsum.
__global__ __launch_bounds__(256) void colscan_scan1_kernel(
    unsigned short* __restrict__ Gin, const unsigned short* __restrict__ Gout,
    int* __restrict__ deg_in, int* __restrict__ deg_out,
    int* __restrict__ lscan, int* __restrict__ bsum, int n) {
  __shared__ int s[256];
  const int tid = threadIdx.x;
  const int i = blockIdx.x * 256 + tid;
  int di = 0;
  if (i < n) {
    int base = 0;
    #pragma unroll 8
    for (int b = 0; b < BC; ++b) {
      int c = Gin[(size_t)b * n + i];
      Gin[(size_t)b * n + i] = (unsigned short)base;
      base += c;
    }
    di = base;
    int dsum = 0;
    #pragma unroll 8
    for (int b = 0; b < BC; ++b) dsum += Gout[(size_t)b * n + i];
    deg_in[i] = di;
    deg_out[i] = dsum;
  }
  s[tid] = di;
  __syncthreads();
  #pragma unroll
  for (int off = 1; off < 256; off <<= 1) {
    int t2 = (tid >= off) ? s[tid - off] : 0;
    __syncthreads();
    s[tid] += t2;
    __syncthreads();
  }
  if (i < n) lscan[i] = s[tid] - di;
  if (tid == 255) bsum[blockIdx.x] = s[255];
}

// scan3: block b reduces bsum[0..b), finalizes row_start + deg^{-1/2}.
__global__ __launch_bounds__(256) void scan3_kernel(
    const int* __restrict__ lscan, const int* __restrict__ bsum,
    const int* __restrict__ deg_out, const int* __restrict__ deg_in,
    int* __restrict__ row_start, float* __restrict__ so, float* __restrict__ si,
    int n, int nE) {
  __shared__ int red[256];
  const int tid = threadIdx.x;
  const int b = blockIdx.x;
  red[tid] = (tid < b) ? bsum[tid] : 0;
  __syncthreads();
  #pragma unroll
  for (int s = 128; s > 0; s >>= 1) {
    if (tid < s) red[tid] += red[tid + s];
    __syncthreads();
  }
  const int off = red[0];
  const int i = b * 256 + tid;
  if (b == 0 && tid == 0) row_start[n] = nE;
  if (i < n) {
    row_start[i] = lscan[i] + off;
    int dO = deg_out[i];
    int dI = deg_in[i];
    so[i] = dO > 0 ? rsqrtf((float)dO) : 0.f;
    si[i] = dI > 0 ? rsqrtf((float)dI) : 0.f;
  }
}

// Atomic-free placement (standalone, full occupancy).
__global__ __launch_bounds__(256) void place_kernel(
    const int* __restrict__ src, const int* __restrict__ dst,
    const unsigned short* __restrict__ Gin, const int* __restrict__ row_start,
    unsigned short* __restrict__ sorted, int n, int nE) {
  __shared__ int cnt[RANGE];
  const int rb = blockIdx.x;
  const int r = rb / BC, b = rb % BC;
  const int r0 = r * RANGE;
  for (int i = threadIdx.x; i < RANGE; i += 256) cnt[i] = 0;
  __syncthreads();
  const int chunk = (nE + BC - 1) / BC;
  const int lo = b * chunk, hi = min(lo + chunk, nE);
  for (int e = lo + threadIdx.x; e < hi; e += 256) {
    int d = dst[e];
    unsigned int k = (unsigned int)(d - r0);
    if (k < (unsigned int)RANGE) {
      int rank = atomicAdd(&cnt[k], 1);
      int pos = row_start[d] + (int)Gin[(size_t)b * n + d] + rank;
      sorted[pos] = (unsigned short)src[e];
    }
  }
}

// ---------------------------------------------------------------------------
// MFMA GEMM core: 64x64 tile, 4 waves, wave w owns rows [16w,16w+16).
// Ab/Wt: bf16 in LDS, row stride 72 (144 B: 16B-aligned b128 reads, 2-way
// bank alias = free). Fragments (verified layouts, m89/m91/m120):
//   A: lane holds A[m=lane&15][k=quad*8 .. +8)   (contiguous 16 B)
//   B: lane holds Bt[n=lane&15][k=quad*8 .. +8)  (Bt = W^T rows)
//   C/D: col=lane&15, row=quad*4+reg
__device__ __forceinline__ void mfma_gemm_core(
    const unsigned short* __restrict__ Ab, const unsigned short* __restrict__ Wt,
    unsigned short* __restrict__ H, int row0, int n, int t) {
  const int w = t >> 6, lane = t & 63;
  const int quad = lane >> 4, l15 = lane & 15;
  const short8 a0 = *(const short8*)&Ab[(w * 16 + l15) * 72 + quad * 8];
  const short8 a1 = *(const short8*)&Ab[(w * 16 + l15) * 72 + 32 + quad * 8];
  #pragma unroll
  for (int cg = 0; cg < 4; ++cg) {
    const short8 b0 = *(const short8*)&Wt[(cg * 16 + l15) * 72 + quad * 8];
    const short8 b1 = *(const short8*)&Wt[(cg * 16 + l15) * 72 + 32 + quad * 8];
    floatx4 acc = {0.f, 0.f, 0.f, 0.f};
    acc = __builtin_amdgcn_mfma_f32_16x16x32_bf16(a0, b0, acc, 0, 0, 0);
    acc = __builtin_amdgcn_mfma_f32_16x16x32_bf16(a1, b1, acc, 0, 0, 0);
    #pragma unroll
    for (int reg = 0; reg < 4; ++reg) {
      int grow = row0 + w * 16 + quad * 4 + reg;
      if (grow < n) H[(size_t)grow * NF + cg * 16 + l15] = f2bf(acc[reg]);
    }
  }
}

// Stage W^T (f32 global -> bf16 LDS, [j][k] stride 72).
__device__ __forceinline__ void stage_wt(
    const float* __restrict__ W, unsigned short* __restrict__ Wt, int t) {
  #pragma unroll
  for (int i = 0; i < 16; ++i) {
    int idx = t + 256 * i;        // [k][j] order, coalesced read
    int k = idx >> 6, j = idx & 63;
    Wt[j * 72 + k] = f2bf(W[idx]);
  }
}

// Layer 1: h1 = bf16((x*so) @ W1), f32 input.
__global__ __launch_bounds__(256) void gemm1_kernel(
    const float* __restrict__ A, const float* __restrict__ so,
    const float* __restrict__ W, unsigned short* __restrict__ H, int n) {
  __shared__ __align__(16) unsigned short Ab[64 * 72];
  __shared__ __align__(16) unsigned short Wt[64 * 72];
  const int t = threadIdx.x;
  stage_wt(W, Wt, t);
  const int row0 = blockIdx.x * 64;
  #pragma unroll
  for (int i = 0; i < 4; ++i) {
    int idx = t + 256 * i;        // 1024 items: row, 16B col group
    int r = idx >> 4, c4 = idx & 15;
    int gr = row0 + r;
    float4 v = {0.f, 0.f, 0.f, 0.f};
    float s = 0.f;
    if (gr < n) {
      v = *(const float4*)&A[(size_t)gr * NF + c4 * 4];
      s = so[gr];
    }
    ushort4 o;
    o.x = f2bf(v.x * s); o.y = f2bf(v.y * s);
    o.z = f2bf(v.z * s); o.w = f2bf(v.w * s);
    *(ushort4*)&Ab[r * 72 + c4 * 4] = o;
  }
  __syncthreads();
  mfma_gemm_core(Ab, Wt, H, row0, n, t);
}

// Layer 2: h2 = bf16(t @ W2), bf16 input.
__global__ __launch_bounds__(256) void gemm2_kernel(
    const unsigned short* __restrict__ Tb, const float* __restrict__ W,
    unsigned short* __restrict__ H, int n) {
  __shared__ __align__(16) unsigned short Ab[64 * 72];
  __shared__ __align__(16) unsigned short Wt[64 * 72];
  const int t = threadIdx.x;
  stage_wt(W, Wt, t);
  const int row0 = blockIdx.x * 64;
  #pragma unroll
  for (int i = 0; i < 4; ++i) {
    int idx = t + 256 * i;
    int r = idx >> 4, c4 = idx & 15;
    int gr = row0 + r;
    ushort4 v = {0, 0, 0, 0};
    if (gr < n) v = *(const ushort4*)&Tb[(size_t)gr * NF + c4 * 4];
    *(ushort4*)&Ab[r * 72 + c4 * 4] = v;
  }
  __syncthreads();
  mfma_gemm_core(Ab, Wt, H, row0, n, t);
}

// ---------------------------------------------------------------------------
// Gather/accumulate (one wave per node, bf16 rows = 128 B, 8 rows per VMEM
// instruction; butterfly leaves the full row sum in every lane:
// features (lane&7)*8 .. +7 in acc[0..7]).
__device__ __forceinline__ void gather_sum(
    const unsigned short* __restrict__ H, const unsigned short* __restrict__ srcs,
    int beg, int end, int g, int c, float* acc) {
  const float4* Hv = (const float4*)H;
  int e = beg;
  for (; e + 16 <= end; e += 16) {
    int ia = srcs[e + g];
    int ib = srcs[e + 8 + g];
    float4 va = Hv[(size_t)ia * 8 + c];
    float4 vb = Hv[(size_t)ib * 8 + c];
    const unsigned int* pa = (const unsigned int*)&va;
    const unsigned int* pb = (const unsigned int*)&vb;
    #pragma unroll
    for (int k = 0; k < 4; ++k) {
      acc[2 * k]     += __uint_as_float(pa[k] << 16) + __uint_as_float(pb[k] << 16);
      acc[2 * k + 1] += __uint_as_float(pa[k] & 0xffff0000u) + __uint_as_float(pb[k] & 0xffff0000u);
    }
  }
  if (e + 8 <= end) {
    int ia = srcs[e + g];
    float4 va = Hv[(size_t)ia * 8 + c];
    const unsigned int* pa = (const unsigned int*)&va;
    #pragma unroll
    for (int k = 0; k < 4; ++k) {
      acc[2 * k]     += __uint_as_float(pa[k] << 16);
      acc[2 * k + 1] += __uint_as_float(pa[k] & 0xffff0000u);
    }
    e += 8;
  }
  if (e < end) {
    int idx = (e + g < end) ? (e + g) : (end - 1);
    float m = (e + g < end) ? 1.f : 0.f;
    int ia = srcs[idx];
    float4 va = Hv[(size_t)ia * 8 + c];
    const unsigned int* pa = (const unsigned int*)&va;
    #pragma unroll
    for (int k = 0; k < 4; ++k) {
      acc[2 * k]     += m * __uint_as_float(pa[k] << 16);
      acc[2 * k + 1] += m * __uint_as_float(pa[k] & 0xffff0000u);
    }
  }
  #pragma unroll
  for (int d = 8; d <= 32; d <<= 1) {
    #pragma unroll
    for (int k = 0; k < 8; ++k) acc[k] += __shfl_xor(acc[k], d);
  }
}

// Layer-1 aggregation: t = bf16(relu(segsum(h1)*si + b1) * so).
__global__ __launch_bounds__(256) void agg1_kernel(
    const unsigned short* __restrict__ H1, const int* __restrict__ row_start,
    const unsigned short* __restrict__ srcs, const float* __restrict__ si,
    const float* __restrict__ so, const float* __restrict__ b1,
    unsigned short* __restrict__ T, int n) {
  int node = blockIdx.x * 4 + (threadIdx.x >> 6);
  if (node >= n) return;
  const int lane = threadIdx.x & 63;
  const int g = lane >> 3;
  const int c = lane & 7;
  float acc[8] = {0, 0, 0, 0, 0, 0, 0, 0};
  gather_sum(H1, srcs, row_start[node], row_start[node + 1], g, c, acc);
  if (g == 0) {
    const float sin = si[node];
    const float son = so[node];
    ushort4 o0, o1;
    float v;
    v = fmaxf(fmaf(acc[0], sin, b1[c * 8 + 0]), 0.f) * son; o0.x = f2bf(v);
    v = fmaxf(fmaf(acc[1], sin, b1[c * 8 + 1]), 0.f) * son; o0.y = f2bf(v);
    v = fmaxf(fmaf(acc[2], sin, b1[c * 8 + 2]), 0.f) * son; o0.z = f2bf(v);
    v = fmaxf(fmaf(acc[3], sin, b1[c * 8 + 3]), 0.f) * son; o0.w = f2bf(v);
    v = fmaxf(fmaf(acc[4], sin, b1[c * 8 + 4]), 0.f) * son; o1.x = f2bf(v);
    v = fmaxf(fmaf(acc[5], sin, b1[c * 8 + 5]), 0.f) * son; o1.y = f2bf(v);
    v = fmaxf(fmaf(acc[6], sin, b1[c * 8 + 6]), 0.f) * son; o1.z = f2bf(v);
    v = fmaxf(fmaf(acc[7], sin, b1[c * 8 + 7]), 0.f) * son; o1.w = f2bf(v);
    *(ushort4*)&T[(size_t)node * NF + c * 8]     = o0;
    *(ushort4*)&T[(size_t)node * NF + c * 8 + 4] = o1;
  }
}

// Layer-2 aggregation: out = segsum(h2)*si + b2 (f32).
__global__ __launch_bounds__(256) void agg2_kernel(
    const unsigned short* __restrict__ H2, const int* __restrict__ row_start,
    const unsigned short* __restrict__ srcs, const float* __restrict__ si,
    const float* __restrict__ b2, float* __restrict__ out, int n) {
  int node = blockIdx.x * 4 + (threadIdx.x >> 6);
  if (node >= n) return;
  const int lane = threadIdx.x & 63;
  const int g = lane >> 3;
  const int c = lane & 7;
  float acc[8] = {0, 0, 0, 0, 0, 0, 0, 0};
  gather_sum(H2, srcs, row_start[node], row_start[node + 1], g, c, acc);
  if (g == 0) {
    const float sin = si[node];
    const float4 b4a = *(const float4*)&b2[c * 8];
    const float4 b4b = *(const float4*)&b2[c * 8 + 4];
    float4 r0, r1;
    r0.x = fmaf(acc[0], sin, b4a.x);
    r0.y = fmaf(acc[1], sin, b4a.y);
    r0.z = fmaf(acc[2], sin, b4a.z);
    r0.w = fmaf(acc[3], sin, b4a.w);
    r1.x = fmaf(acc[4], sin, b4b.x);
    r1.y = fmaf(acc[5], sin, b4b.y);
    r1.z = fmaf(acc[6], sin, b4b.z);
    r1.w = fmaf(acc[7], sin, b4b.w);
    *(float4*)&out[(size_t)node * NF + c * 8]     = r0;
    *(float4*)&out[(size_t)node * NF + c * 8 + 4] = r1;
  }
}

// ---------------------------------------------------------------------------
extern "C" void kernel_launch(void* const* d_in, const int* in_sizes, int n_in,
                              void* d_out, int out_size, void* d_ws, size_t ws_size,
                              hipStream_t stream) {
  const float* x  = (const float*)d_in[0];
  const float* W1 = (const float*)d_in[1];
  const float* b1 = (const float*)d_in[2];
  const float* W2 = (const float*)d_in[3];
  const float* b2 = (const float*)d_in[4];
  const int* src  = (const int*)d_in[5];
  const int* dst  = (const int*)d_in[6];
  float* out = (float*)d_out;

  const int N = in_sizes[0] / NF;   // 50000 (< 65536 for ushort ids)
  const int E = in_sizes[5];        // 800000
  const int NB = (N + 255) / 256;   // 196 <= 256
  const int R  = (N + RANGE - 1) / RANGE;  // 7

  // Workspace (~23 MB), no memsets needed (everything written before read).
  char* ws = (char*)d_ws;
  size_t p = 0;
  auto alloc = [&](size_t bytes) -> void* {
    void* r = ws + p;
    p = (p + bytes + 255) & ~(size_t)255;
    return r;
  };
  int*   deg_out_i  = (int*)  alloc((size_t)N * 4);
  int*   deg_in_i   = (int*)  alloc((size_t)N * 4);
  float* so         = (float*)alloc((size_t)N * 4);
  float* si         = (float*)alloc((size_t)N * 4);
  int*   row_start  = (int*)  alloc((size_t)(N + 1) * 4);
  int*   bsum       = (int*)  alloc((size_t)NB * 4);
  int*   lscan      = (int*)  alloc((size_t)N * 4);
  unsigned short* sorted_u16 = (unsigned short*)alloc((size_t)E * 2);
  unsigned short* h1   = (unsigned short*)alloc((size_t)N * NF * 2);  // bf16; reused as h2
  unsigned short* tb   = (unsigned short*)alloc((size_t)N * NF * 2);  // bf16 t
  unsigned short* G_in  = (unsigned short*)alloc((size_t)BC * N * 2); // 3.2 MB
  unsigned short* G_out = (unsigned short*)alloc((size_t)BC * N * 2); // 3.2 MB
  unsigned short* h2 = h1;  // h1 dead once agg1 completes; gemm2 runs after

  // 1. per-(range,chunk) histograms for both endpoints
  hist_kernel<<<2 * R * BC, 256, 0, stream>>>(src, dst, G_out, G_in, N, E, R);

  // 2. fused column-scan (per-chunk bases + degrees) + block scan
  colscan_scan1_kernel<<<NB, 256, 0, stream>>>(G_in, G_out, deg_in_i, deg_out_i,
                                               lscan, bsum, N);

  // 3. row_start + so/si
  scan3_kernel<<<NB, 256, 0, stream>>>(lscan, bsum, deg_out_i, deg_in_i,
                                       row_start, so, si, N, E);

  // 4. atomic-free placement
  place_kernel<<<R * BC, 256, 0, stream>>>(src, dst, G_in, row_start,
                                           sorted_u16, N, E);

  const int ggrid = (N + 63) / 64;
  const int agrid = (N + 3) / 4;

  // 5. layer 1: h1 = bf16((x*so) @ W1)   [MFMA]
  gemm1_kernel<<<ggrid, 256, 0, stream>>>(x, so, W1, h1, N);

  // 6. t = bf16(relu(segsum(h1)*si + b1) * so)
  agg1_kernel<<<agrid, 256, 0, stream>>>(h1, row_start, sorted_u16, si, so, b1, tb, N);

  // 7. h2 = bf16(t @ W2)   [MFMA]
  gemm2_kernel<<<ggrid, 256, 0, stream>>>(tb, W2, h2, N);

  // 8. out = segsum(h2)*si + b2
  agg2_kernel<<<agrid, 256, 0, stream>>>(h2, row_start, sorted_u16, si, b2, out, N);
}

// Round 11
// 197.825 us; speedup vs baseline: 1.7623x; 1.0955x over previous
//
#include <hip/hip_runtime.h>

#define NF 64        // feature width
#define BC 32        // edge chunks
#define RANGE 8192   // node-range for LDS histograms (32 KB int counters)

typedef __attribute__((ext_vector_type(8))) short short8;    // 8 bf16 (4 VGPRs)
typedef __attribute__((ext_vector_type(4))) float floatx4;   // MFMA accumulator

// f32 -> bf16 round-to-nearest-even
__device__ __forceinline__ unsigned short f2bf(float f) {
  unsigned int u = __float_as_uint(f);
  return (unsigned short)((u + 0x7fffu + ((u >> 16) & 1u)) >> 16);
}

// ---------------------------------------------------------------------------
// Per-(range,chunk) LDS histograms. kind 0: dst -> Gin[b][node] AND captures
// rank[e] (edge's arrival index within its (chunk,node) bucket — any
// bijection works since segment-sum is order-independent). kind 1: src ->
// Gout[b][node]. Each edge's dst lies in exactly one range -> rank[e] is
// written exactly once.
__global__ __launch_bounds__(256) void hist_kernel(
    const int* __restrict__ src, const int* __restrict__ dst,
    unsigned short* __restrict__ Gout, unsigned short* __restrict__ Gin,
    unsigned char* __restrict__ rank, int n, int nE, int R) {
  __shared__ int cnt[RANGE];
  const int rb = blockIdx.x % (R * BC);
  const int kind = blockIdx.x / (R * BC);
  const int r = rb / BC, b = rb % BC;
  const int r0 = r * RANGE;
  for (int i = threadIdx.x; i < RANGE; i += 256) cnt[i] = 0;
  __syncthreads();
  const int chunk = (nE + BC - 1) / BC;
  const int lo = b * chunk, hi = min(lo + chunk, nE);
  if (kind == 0) {
    for (int e = lo + threadIdx.x; e < hi; e += 256) {
      unsigned int k = (unsigned int)(dst[e] - r0);
      if (k < (unsigned int)RANGE) {
        int old = atomicAdd(&cnt[k], 1);
        rank[e] = (unsigned char)old;   // coalesced-ish store, exactly once
      }
    }
    __syncthreads();
    for (int i = threadIdx.x; i < RANGE; i += 256) {
      int nidx = r0 + i;
      if (nidx < n) Gin[(size_t)b * n + nidx] = (unsigned short)cnt[i];
    }
  } else {
    for (int e = lo + threadIdx.x; e < hi; e += 256) {
      unsigned int k = (unsigned int)(src[e] - r0);
      if (k < (unsigned int)RANGE) atomicAdd(&cnt[k], 1);
    }
    __syncthreads();
    for (int i = threadIdx.x; i < RANGE; i += 256) {
      int nidx = r0 + i;
      if (nidx < n) Gout[(size_t)b * n + nidx] = (unsigned short)cnt[i];
    }
  }
}

// ---------------------------------------------------------------------------
// Fused colscan + scan1: per node, exclusive scan of Gin down the chunks
// (in place -> per-chunk bases) -> deg_in; sum Gout -> deg_out; then
// block-scan deg_in -> lscan + bsum.
__global__ __launch_bounds__(256) void colscan_scan1_kernel(
    unsigned short* __restrict__ Gin, const unsigned short* __restrict__ Gout,
    int* __restrict__ deg_in, int* __restrict__ deg_out,
    int* __restrict__ lscan, int* __restrict__ bsum, int n) {
  __shared__ int s[256];
  const int tid = threadIdx.x;
  const int i = blockIdx.x * 256 + tid;
  int di = 0;
  if (i < n) {
    int base = 0;
    #pragma unroll 8
    for (int b = 0; b < BC; ++b) {
      int c = Gin[(size_t)b * n + i];
      Gin[(size_t)b * n + i] = (unsigned short)base;
      base += c;
    }
    di = base;
    int dsum = 0;
    #pragma unroll 8
    for (int b = 0; b < BC; ++b) dsum += Gout[(size_t)b * n + i];
    deg_in[i] = di;
    deg_out[i] = dsum;
  }
  s[tid] = di;
  __syncthreads();
  #pragma unroll
  for (int off = 1; off < 256; off <<= 1) {
    int t2 = (tid >= off) ? s[tid - off] : 0;
    __syncthreads();
    s[tid] += t2;
    __syncthreads();
  }
  if (i < n) lscan[i] = s[tid] - di;
  if (tid == 255) bsum[blockIdx.x] = s[255];
}

// scan3: block b reduces bsum[0..b), finalizes row_start + deg^{-1/2}, and
// materializes base[b][i] = row_start[i] + Gin[b][i] (32 coalesced passes)
// so place needs ONE scattered read per edge.
__global__ __launch_bounds__(256) void scan3_kernel(
    const int* __restrict__ lscan, const int* __restrict__ bsum,
    const int* __restrict__ deg_out, const int* __restrict__ deg_in,
    const unsigned short* __restrict__ Gin, int* __restrict__ base,
    int* __restrict__ row_start, float* __restrict__ so, float* __restrict__ si,
    int n, int nE) {
  __shared__ int red[256];
  const int tid = threadIdx.x;
  const int b = blockIdx.x;
  red[tid] = (tid < b) ? bsum[tid] : 0;
  __syncthreads();
  #pragma unroll
  for (int s = 128; s > 0; s >>= 1) {
    if (tid < s) red[tid] += red[tid + s];
    __syncthreads();
  }
  const int off = red[0];
  const int i = b * 256 + tid;
  if (b == 0 && tid == 0) row_start[n] = nE;
  if (i < n) {
    int rs = lscan[i] + off;
    row_start[i] = rs;
    int dO = deg_out[i];
    int dI = deg_in[i];
    so[i] = dO > 0 ? rsqrtf((float)dO) : 0.f;
    si[i] = dI > 0 ? rsqrtf((float)dI) : 0.f;
    #pragma unroll 8
    for (int c = 0; c < BC; ++c)
      base[(size_t)c * n + i] = rs + (int)Gin[(size_t)c * n + i];
  }
}

// Parallel atomic-free placement: one thread per edge, no LDS (the r10
// version's 224-block LDS rank rebuild ran at 1 block/CU, latency-bound).
__global__ __launch_bounds__(256) void place_kernel(
    const int* __restrict__ src, const int* __restrict__ dst,
    const unsigned char* __restrict__ rank, const int* __restrict__ base,
    unsigned short* __restrict__ sorted, int n, int nE, int chunk) {
  int e = blockIdx.x * 256 + threadIdx.x;
  if (e >= nE) return;
  int d = dst[e];
  int b = e / chunk;
  int pos = base[(size_t)b * n + d] + (int)rank[e];
  sorted[pos] = (unsigned short)src[e];
}

// ---------------------------------------------------------------------------
// MFMA GEMM core: 64x64 tile, 4 waves, wave w owns rows [16w,16w+16).
// Ab/Wt: bf16 in LDS, row stride 72 (144 B: 16B-aligned b128 reads, 2-way
// bank alias = free). Verified layouts (m89/m91):
//   A: lane holds A[m=lane&15][k=quad*8 .. +8) ; B from Bt=W^T rows
//   C/D: col=lane&15, row=quad*4+reg
__device__ __forceinline__ void mfma_gemm_core(
    const unsigned short* __restrict__ Ab, const unsigned short* __restrict__ Wt,
    unsigned short* __restrict__ H, int row0, int n, int t) {
  const int w = t >> 6, lane = t & 63;
  const int quad = lane >> 4, l15 = lane & 15;
  const short8 a0 = *(const short8*)&Ab[(w * 16 + l15) * 72 + quad * 8];
  const short8 a1 = *(const short8*)&Ab[(w * 16 + l15) * 72 + 32 + quad * 8];
  #pragma unroll
  for (int cg = 0; cg < 4; ++cg) {
    const short8 b0 = *(const short8*)&Wt[(cg * 16 + l15) * 72 + quad * 8];
    const short8 b1 = *(const short8*)&Wt[(cg * 16 + l15) * 72 + 32 + quad * 8];
    floatx4 acc = {0.f, 0.f, 0.f, 0.f};
    acc = __builtin_amdgcn_mfma_f32_16x16x32_bf16(a0, b0, acc, 0, 0, 0);
    acc = __builtin_amdgcn_mfma_f32_16x16x32_bf16(a1, b1, acc, 0, 0, 0);
    #pragma unroll
    for (int reg = 0; reg < 4; ++reg) {
      int grow = row0 + w * 16 + quad * 4 + reg;
      if (grow < n) H[(size_t)grow * NF + cg * 16 + l15] = f2bf(acc[reg]);
    }
  }
}

// Stage W^T (f32 global -> bf16 LDS, [j][k] stride 72).
__device__ __forceinline__ void stage_wt(
    const float* __restrict__ W, unsigned short* __restrict__ Wt, int t) {
  #pragma unroll
  for (int i = 0; i < 16; ++i) {
    int idx = t + 256 * i;        // [k][j] order, coalesced read
    int k = idx >> 6, j = idx & 63;
    Wt[j * 72 + k] = f2bf(W[idx]);
  }
}

// Layer 1: h1 = bf16((x*so) @ W1), f32 input.
__global__ __launch_bounds__(256) void gemm1_kernel(
    const float* __restrict__ A, const float* __restrict__ so,
    const float* __restrict__ W, unsigned short* __restrict__ H, int n) {
  __shared__ __align__(16) unsigned short Ab[64 * 72];
  __shared__ __align__(16) unsigned short Wt[64 * 72];
  const int t = threadIdx.x;
  stage_wt(W, Wt, t);
  const int row0 = blockIdx.x * 64;
  #pragma unroll
  for (int i = 0; i < 4; ++i) {
    int idx = t + 256 * i;        // 1024 items: row, 16B col group
    int r = idx >> 4, c4 = idx & 15;
    int gr = row0 + r;
    float4 v = {0.f, 0.f, 0.f, 0.f};
    float s = 0.f;
    if (gr < n) {
      v = *(const float4*)&A[(size_t)gr * NF + c4 * 4];
      s = so[gr];
    }
    ushort4 o;
    o.x = f2bf(v.x * s); o.y = f2bf(v.y * s);
    o.z = f2bf(v.z * s); o.w = f2bf(v.w * s);
    *(ushort4*)&Ab[r * 72 + c4 * 4] = o;
  }
  __syncthreads();
  mfma_gemm_core(Ab, Wt, H, row0, n, t);
}

// Layer 2: h2 = bf16(t @ W2), bf16 input.
__global__ __launch_bounds__(256) void gemm2_kernel(
    const unsigned short* __restrict__ Tb, const float* __restrict__ W,
    unsigned short* __restrict__ H, int n) {
  __shared__ __align__(16) unsigned short Ab[64 * 72];
  __shared__ __align__(16) unsigned short Wt[64 * 72];
  const int t = threadIdx.x;
  stage_wt(W, Wt, t);
  const int row0 = blockIdx.x * 64;
  #pragma unroll
  for (int i = 0; i < 4; ++i) {
    int idx = t + 256 * i;
    int r = idx >> 4, c4 = idx & 15;
    int gr = row0 + r;
    ushort4 v = {0, 0, 0, 0};
    if (gr < n) v = *(const ushort4*)&Tb[(size_t)gr * NF + c4 * 4];
    *(ushort4*)&Ab[r * 72 + c4 * 4] = v;
  }
  __syncthreads();
  mfma_gemm_core(Ab, Wt, H, row0, n, t);
}

// ---------------------------------------------------------------------------
// Gather/accumulate (one wave per node, bf16 rows = 128 B, 8 rows per VMEM
// instruction; butterfly leaves the full row sum in every lane:
// features (lane&7)*8 .. +7 in acc[0..7]).
__device__ __forceinline__ void gather_sum(
    const unsigned short* __restrict__ H, const unsigned short* __restrict__ srcs,
    int beg, int end, int g, int c, float* acc) {
  const float4* Hv = (const float4*)H;
  int e = beg;
  for (; e + 16 <= end; e += 16) {
    int ia = srcs[e + g];
    int ib = srcs[e + 8 + g];
    float4 va = Hv[(size_t)ia * 8 + c];
    float4 vb = Hv[(size_t)ib * 8 + c];
    const unsigned int* pa = (const unsigned int*)&va;
    const unsigned int* pb = (const unsigned int*)&vb;
    #pragma unroll
    for (int k = 0; k < 4; ++k) {
      acc[2 * k]     += __uint_as_float(pa[k] << 16) + __uint_as_float(pb[k] << 16);
      acc[2 * k + 1] += __uint_as_float(pa[k] & 0xffff0000u) + __uint_as_float(pb[k] & 0xffff0000u);
    }
  }
  if (e + 8 <= end) {
    int ia = srcs[e + g];
    float4 va = Hv[(size_t)ia * 8 + c];
    const unsigned int* pa = (const unsigned int*)&va;
    #pragma unroll
    for (int k = 0; k < 4; ++k) {
      acc[2 * k]     += __uint_as_float(pa[k] << 16);
      acc[2 * k + 1] += __uint_as_float(pa[k] & 0xffff0000u);
    }
    e += 8;
  }
  if (e < end) {
    int idx = (e + g < end) ? (e + g) : (end - 1);
    float m = (e + g < end) ? 1.f : 0.f;
    int ia = srcs[idx];
    float4 va = Hv[(size_t)ia * 8 + c];
    const unsigned int* pa = (const unsigned int*)&va;
    #pragma unroll
    for (int k = 0; k < 4; ++k) {
      acc[2 * k]     += m * __uint_as_float(pa[k] << 16);
      acc[2 * k + 1] += m * __uint_as_float(pa[k] & 0xffff0000u);
    }
  }
  #pragma unroll
  for (int d = 8; d <= 32; d <<= 1) {
    #pragma unroll
    for (int k = 0; k < 8; ++k) acc[k] += __shfl_xor(acc[k], d);
  }
}

// Layer-1 aggregation: t = bf16(relu(segsum(h1)*si + b1) * so).
__global__ __launch_bounds__(256) void agg1_kernel(
    const unsigned short* __restrict__ H1, const int* __restrict__ row_start,
    const unsigned short* __restrict__ srcs, const float* __restrict__ si,
    const float* __restrict__ so, const float* __restrict__ b1,
    unsigned short* __restrict__ T, int n) {
  int node = blockIdx.x * 4 + (threadIdx.x >> 6);
  if (node >= n) return;
  const int lane = threadIdx.x & 63;
  const int g = lane >> 3;
  const int c = lane & 7;
  float acc[8] = {0, 0, 0, 0, 0, 0, 0, 0};
  gather_sum(H1, srcs, row_start[node], row_start[node + 1], g, c, acc);
  if (g == 0) {
    const float sin = si[node];
    const float son = so[node];
    ushort4 o0, o1;
    float v;
    v = fmaxf(fmaf(acc[0], sin, b1[c * 8 + 0]), 0.f) * son; o0.x = f2bf(v);
    v = fmaxf(fmaf(acc[1], sin, b1[c * 8 + 1]), 0.f) * son; o0.y = f2bf(v);
    v = fmaxf(fmaf(acc[2], sin, b1[c * 8 + 2]), 0.f) * son; o0.z = f2bf(v);
    v = fmaxf(fmaf(acc[3], sin, b1[c * 8 + 3]), 0.f) * son; o0.w = f2bf(v);
    v = fmaxf(fmaf(acc[4], sin, b1[c * 8 + 4]), 0.f) * son; o1.x = f2bf(v);
    v = fmaxf(fmaf(acc[5], sin, b1[c * 8 + 5]), 0.f) * son; o1.y = f2bf(v);
    v = fmaxf(fmaf(acc[6], sin, b1[c * 8 + 6]), 0.f) * son; o1.z = f2bf(v);
    v = fmaxf(fmaf(acc[7], sin, b1[c * 8 + 7]), 0.f) * son; o1.w = f2bf(v);
    *(ushort4*)&T[(size_t)node * NF + c * 8]     = o0;
    *(ushort4*)&T[(size_t)node * NF + c * 8 + 4] = o1;
  }
}

// Layer-2 aggregation: out = segsum(h2)*si + b2 (f32).
__global__ __launch_bounds__(256) void agg2_kernel(
    const unsigned short* __restrict__ H2, const int* __restrict__ row_start,
    const unsigned short* __restrict__ srcs, const float* __restrict__ si,
    const float* __restrict__ b2, float* __restrict__ out, int n) {
  int node = blockIdx.x * 4 + (threadIdx.x >> 6);
  if (node >= n) return;
  const int lane = threadIdx.x & 63;
  const int g = lane >> 3;
  const int c = lane & 7;
  float acc[8] = {0, 0, 0, 0, 0, 0, 0, 0};
  gather_sum(H2, srcs, row_start[node], row_start[node + 1], g, c, acc);
  if (g == 0) {
    const float sin = si[node];
    const float4 b4a = *(const float4*)&b2[c * 8];
    const float4 b4b = *(const float4*)&b2[c * 8 + 4];
    float4 r0, r1;
    r0.x = fmaf(acc[0], sin, b4a.x);
    r0.y = fmaf(acc[1], sin, b4a.y);
    r0.z = fmaf(acc[2], sin, b4a.z);
    r0.w = fmaf(acc[3], sin, b4a.w);
    r1.x = fmaf(acc[4], sin, b4b.x);
    r1.y = fmaf(acc[5], sin, b4b.y);
    r1.z = fmaf(acc[6], sin, b4b.z);
    r1.w = fmaf(acc[7], sin, b4b.w);
    *(float4*)&out[(size_t)node * NF + c * 8]     = r0;
    *(float4*)&out[(size_t)node * NF + c * 8 + 4] = r1;
  }
}

// ---------------------------------------------------------------------------
extern "C" void kernel_launch(void* const* d_in, const int* in_sizes, int n_in,
                              void* d_out, int out_size, void* d_ws, size_t ws_size,
                              hipStream_t stream) {
  const float* x  = (const float*)d_in[0];
  const float* W1 = (const float*)d_in[1];
  const float* b1 = (const float*)d_in[2];
  const float* W2 = (const float*)d_in[3];
  const float* b2 = (const float*)d_in[4];
  const int* src  = (const int*)d_in[5];
  const int* dst  = (const int*)d_in[6];
  float* out = (float*)d_out;

  const int N = in_sizes[0] / NF;   // 50000 (< 65536 for ushort ids)
  const int E = in_sizes[5];        // 800000
  const int NB = (N + 255) / 256;   // 196 <= 256
  const int R  = (N + RANGE - 1) / RANGE;  // 7
  const int CH = (E + BC - 1) / BC; // chunk length

  // Workspace (~30 MB), no memsets needed (everything written before read).
  char* ws = (char*)d_ws;
  size_t p = 0;
  auto alloc = [&](size_t bytes) -> void* {
    void* r = ws + p;
    p = (p + bytes + 255) & ~(size_t)255;
    return r;
  };
  int*   deg_out_i  = (int*)  alloc((size_t)N * 4);
  int*   deg_in_i   = (int*)  alloc((size_t)N * 4);
  float* so         = (float*)alloc((size_t)N * 4);
  float* si         = (float*)alloc((size_t)N * 4);
  int*   row_start  = (int*)  alloc((size_t)(N + 1) * 4);
  int*   bsum       = (int*)  alloc((size_t)NB * 4);
  int*   lscan      = (int*)  alloc((size_t)N * 4);
  unsigned short* sorted_u16 = (unsigned short*)alloc((size_t)E * 2);
  unsigned short* h1   = (unsigned short*)alloc((size_t)N * NF * 2);  // bf16; reused as h2
  unsigned short* tb   = (unsigned short*)alloc((size_t)N * NF * 2);  // bf16 t
  unsigned short* G_in  = (unsigned short*)alloc((size_t)BC * N * 2); // 3.2 MB
  unsigned short* G_out = (unsigned short*)alloc((size_t)BC * N * 2); // 3.2 MB
  unsigned char*  rank  = (unsigned char*)alloc((size_t)E);           // 0.8 MB
  int*            base  = (int*)alloc((size_t)BC * N * 4);            // 6.4 MB
  unsigned short* h2 = h1;  // h1 dead once agg1 completes; gemm2 runs after

  // 1. per-(range,chunk) histograms for both endpoints (+ rank capture)
  hist_kernel<<<2 * R * BC, 256, 0, stream>>>(src, dst, G_out, G_in, rank, N, E, R);

  // 2. fused column-scan (per-chunk bases + degrees) + block scan
  colscan_scan1_kernel<<<NB, 256, 0, stream>>>(G_in, G_out, deg_in_i, deg_out_i,
                                               lscan, bsum, N);

  // 3. row_start + so/si + base matrix
  scan3_kernel<<<NB, 256, 0, stream>>>(lscan, bsum, deg_out_i, deg_in_i,
                                       G_in, base, row_start, so, si, N, E);

  // 4. parallel atomic-free placement (one thread per edge)
  place_kernel<<<(E + 255) / 256, 256, 0, stream>>>(src, dst, rank, base,
                                                    sorted_u16, N, E, CH);

  const int ggrid = (N + 63) / 64;
  const int agrid = (N + 3) / 4;

  // 5. layer 1: h1 = bf16((x*so) @ W1)   [MFMA]
  gemm1_kernel<<<ggrid, 256, 0, stream>>>(x, so, W1, h1, N);

  // 6. t = bf16(relu(segsum(h1)*si + b1) * so)
  agg1_kernel<<<agrid, 256, 0, stream>>>(h1, row_start, sorted_u16, si, so, b1, tb, N);

  // 7. h2 = bf16(t @ W2)   [MFMA]
  gemm2_kernel<<<ggrid, 256, 0, stream>>>(tb, W2, h2, N);

  // 8. out = segsum(h2)*si + b2
  agg2_kernel<<<agrid, 256, 0, stream>>>(h2, row_start, sorted_u16, si, b2, out, N);
}

// Round 12
// 185.136 us; speedup vs baseline: 1.8831x; 1.0685x over previous
//
#include <hip/hip_runtime.h>

#define NF 64        // feature width
#define BC 64        // edge chunks (12.5K edges each)
#define RANGE 8192   // node-range for LDS histograms (32 KB int counters)

typedef __attribute__((ext_vector_type(8))) short short8;    // 8 bf16 (4 VGPRs)
typedef __attribute__((ext_vector_type(4))) float floatx4;   // MFMA accumulator

// f32 -> bf16 round-to-nearest-even
__device__ __forceinline__ unsigned short f2bf(float f) {
  unsigned int u = __float_as_uint(f);
  return (unsigned short)((u + 0x7fffu + ((u >> 16) & 1u)) >> 16);
}

// ---------------------------------------------------------------------------
// Per-(range,chunk) LDS histograms, int4-vectorized edge loads.
// kind 0: dst -> Gin[b][node], captures rank[e] (arrival index within the
// (chunk,node) bucket; any bijection works for a segment-sum).
// kind 1: src -> Gout[b][node].
__global__ __launch_bounds__(256) void hist_kernel(
    const int* __restrict__ src, const int* __restrict__ dst,
    unsigned short* __restrict__ Gout, unsigned short* __restrict__ Gin,
    unsigned char* __restrict__ rank, int n, int nE, int R, int chunk) {
  __shared__ int cnt[RANGE];
  const int rb = blockIdx.x % (R * BC);
  const int kind = blockIdx.x / (R * BC);
  const int r = rb / BC, b = rb % BC;
  const int r0 = r * RANGE;
  for (int i = threadIdx.x; i < RANGE; i += 256) cnt[i] = 0;
  __syncthreads();
  const int lo = b * chunk, hi = min(lo + chunk, nE);
  if (hi <= lo) return;  // safe: no counts in this chunk -> all-zero flush below unreachable only if block has no nodes; keep flush
  const int* keys = kind ? src : dst;
  const int n4 = (hi - lo) >> 2;              // int4 groups (lo is 4-aligned)
  const int4* keys4 = (const int4*)(keys + lo);
  if (kind == 0) {
    for (int i = threadIdx.x; i < n4; i += 256) {
      int4 v = keys4[i];
      int e0 = lo + 4 * i;
      unsigned int k;
      k = (unsigned int)(v.x - r0);
      if (k < (unsigned int)RANGE) rank[e0 + 0] = (unsigned char)atomicAdd(&cnt[k], 1);
      k = (unsigned int)(v.y - r0);
      if (k < (unsigned int)RANGE) rank[e0 + 1] = (unsigned char)atomicAdd(&cnt[k], 1);
      k = (unsigned int)(v.z - r0);
      if (k < (unsigned int)RANGE) rank[e0 + 2] = (unsigned char)atomicAdd(&cnt[k], 1);
      k = (unsigned int)(v.w - r0);
      if (k < (unsigned int)RANGE) rank[e0 + 3] = (unsigned char)atomicAdd(&cnt[k], 1);
    }
    for (int e = lo + 4 * n4 + threadIdx.x; e < hi; e += 256) {
      unsigned int k = (unsigned int)(keys[e] - r0);
      if (k < (unsigned int)RANGE) rank[e] = (unsigned char)atomicAdd(&cnt[k], 1);
    }
    __syncthreads();
    for (int i = threadIdx.x; i < RANGE; i += 256) {
      int nidx = r0 + i;
      if (nidx < n) Gin[(size_t)b * n + nidx] = (unsigned short)cnt[i];
    }
  } else {
    for (int i = threadIdx.x; i < n4; i += 256) {
      int4 v = keys4[i];
      unsigned int k;
      k = (unsigned int)(v.x - r0);
      if (k < (unsigned int)RANGE) atomicAdd(&cnt[k], 1);
      k = (unsigned int)(v.y - r0);
      if (k < (unsigned int)RANGE) atomicAdd(&cnt[k], 1);
      k = (unsigned int)(v.z - r0);
      if (k < (unsigned int)RANGE) atomicAdd(&cnt[k], 1);
      k = (unsigned int)(v.w - r0);
      if (k < (unsigned int)RANGE) atomicAdd(&cnt[k], 1);
    }
    for (int e = lo + 4 * n4 + threadIdx.x; e < hi; e += 256) {
      unsigned int k = (unsigned int)(keys[e] - r0);
      if (k < (unsigned int)RANGE) atomicAdd(&cnt[k], 1);
    }
    __syncthreads();
    for (int i = threadIdx.x; i < RANGE; i += 256) {
      int nidx = r0 + i;
      if (nidx < n) Gout[(size_t)b * n + nidx] = (unsigned short)cnt[i];
    }
  }
}

// ---------------------------------------------------------------------------
// Fused colscan + scan1: per node, exclusive scan of Gin down the chunks
// (in place -> per-chunk bases) -> deg_in; sum Gout -> deg_out; then
// block-scan deg_in -> lscan + bsum.
__global__ __launch_bounds__(256) void colscan_scan1_kernel(
    unsigned short* __restrict__ Gin, const unsigned short* __restrict__ Gout,
    int* __restrict__ deg_in, int* __restrict__ deg_out,
    int* __restrict__ lscan, int* __restrict__ bsum, int n) {
  __shared__ int s[256];
  const int tid = threadIdx.x;
  const int i = blockIdx.x * 256 + tid;
  int di = 0;
  if (i < n) {
    int base = 0;
    #pragma unroll 8
    for (int b = 0; b < BC; ++b) {
      int c = Gin[(size_t)b * n + i];
      Gin[(size_t)b * n + i] = (unsigned short)base;
      base += c;
    }
    di = base;
    int dsum = 0;
    #pragma unroll 8
    for (int b = 0; b < BC; ++b) dsum += Gout[(size_t)b * n + i];
    deg_in[i] = di;
    deg_out[i] = dsum;
  }
  s[tid] = di;
  __syncthreads();
  #pragma unroll
  for (int off = 1; off < 256; off <<= 1) {
    int t2 = (tid >= off) ? s[tid - off] : 0;
    __syncthreads();
    s[tid] += t2;
    __syncthreads();
  }
  if (i < n) lscan[i] = s[tid] - di;
  if (tid == 255) bsum[blockIdx.x] = s[255];
}

// scan3: block b reduces bsum[0..b), finalizes row_start + deg^{-1/2}, and
// materializes base[b][i] = row_start[i] + Gin[b][i] so place needs ONE
// scattered read per edge.
__global__ __launch_bounds__(256) void scan3_kernel(
    const int* __restrict__ lscan, const int* __restrict__ bsum,
    const int* __restrict__ deg_out, const int* __restrict__ deg_in,
    const unsigned short* __restrict__ Gin, int* __restrict__ base,
    int* __restrict__ row_start, float* __restrict__ so, float* __restrict__ si,
    int n, int nE) {
  __shared__ int red[256];
  const int tid = threadIdx.x;
  const int b = blockIdx.x;
  red[tid] = (tid < b) ? bsum[tid] : 0;
  __syncthreads();
  #pragma unroll
  for (int s = 128; s > 0; s >>= 1) {
    if (tid < s) red[tid] += red[tid + s];
    __syncthreads();
  }
  const int off = red[0];
  const int i = b * 256 + tid;
  if (b == 0 && tid == 0) row_start[n] = nE;
  if (i < n) {
    int rs = lscan[i] + off;
    row_start[i] = rs;
    int dO = deg_out[i];
    int dI = deg_in[i];
    so[i] = dO > 0 ? rsqrtf((float)dO) : 0.f;
    si[i] = dI > 0 ? rsqrtf((float)dI) : 0.f;
    #pragma unroll 8
    for (int c = 0; c < BC; ++c)
      base[(size_t)c * n + i] = rs + (int)Gin[(size_t)c * n + i];
  }
}

// ---------------------------------------------------------------------------
// MFMA GEMM core: 64x64 tile, 4 waves, wave w owns rows [16w,16w+16).
// Ab/Wt: bf16 in LDS, row stride 72 (144 B: 16B-aligned b128 reads, 2-way
// bank alias = free). Verified layouts (m89/m91):
//   A: lane holds A[m=lane&15][k=quad*8 .. +8) ; B from Bt=W^T rows
//   C/D: col=lane&15, row=quad*4+reg
__device__ __forceinline__ void mfma_gemm_core(
    const unsigned short* __restrict__ Ab, const unsigned short* __restrict__ Wt,
    unsigned short* __restrict__ H, int row0, int n, int t) {
  const int w = t >> 6, lane = t & 63;
  const int quad = lane >> 4, l15 = lane & 15;
  const short8 a0 = *(const short8*)&Ab[(w * 16 + l15) * 72 + quad * 8];
  const short8 a1 = *(const short8*)&Ab[(w * 16 + l15) * 72 + 32 + quad * 8];
  #pragma unroll
  for (int cg = 0; cg < 4; ++cg) {
    const short8 b0 = *(const short8*)&Wt[(cg * 16 + l15) * 72 + quad * 8];
    const short8 b1 = *(const short8*)&Wt[(cg * 16 + l15) * 72 + 32 + quad * 8];
    floatx4 acc = {0.f, 0.f, 0.f, 0.f};
    acc = __builtin_amdgcn_mfma_f32_16x16x32_bf16(a0, b0, acc, 0, 0, 0);
    acc = __builtin_amdgcn_mfma_f32_16x16x32_bf16(a1, b1, acc, 0, 0, 0);
    #pragma unroll
    for (int reg = 0; reg < 4; ++reg) {
      int grow = row0 + w * 16 + quad * 4 + reg;
      if (grow < n) H[(size_t)grow * NF + cg * 16 + l15] = f2bf(acc[reg]);
    }
  }
}

// Stage W^T (f32 global -> bf16 LDS, [j][k] stride 72).
__device__ __forceinline__ void stage_wt(
    const float* __restrict__ W, unsigned short* __restrict__ Wt, int t) {
  #pragma unroll
  for (int i = 0; i < 16; ++i) {
    int idx = t + 256 * i;        // [k][j] order, coalesced read
    int k = idx >> 6, j = idx & 63;
    Wt[j * 72 + k] = f2bf(W[idx]);
  }
}

// Fused layer-1 GEMM + parallel placement (both depend only on scan3; light
// resources on both branches -> no r5-style occupancy trap; co-residency
// makes the dispatch ~max of the two instead of the sum).
// Blocks [0,ggrid): h1 = bf16((x*so)@W1). Blocks [ggrid,..): one thread per
// edge, pos = base[e/chunk][dst[e]] + rank[e]; sorted[pos] = src[e].
__global__ __launch_bounds__(256) void place_gemm1_kernel(
    const float* __restrict__ A, const float* __restrict__ so,
    const float* __restrict__ W, unsigned short* __restrict__ H, int n, int ggrid,
    const int* __restrict__ src, const int* __restrict__ dst,
    const unsigned char* __restrict__ rank, const int* __restrict__ base,
    unsigned short* __restrict__ sorted, int nE, int chunk) {
  __shared__ __align__(16) unsigned short Ab[64 * 72];
  __shared__ __align__(16) unsigned short Wt[64 * 72];
  const int t = threadIdx.x;
  if ((int)blockIdx.x >= ggrid) {
    int e = (blockIdx.x - ggrid) * 256 + t;
    if (e < nE) {
      int d = dst[e];
      int b = e / chunk;
      sorted[base[(size_t)b * n + d] + (int)rank[e]] = (unsigned short)src[e];
    }
    return;
  }
  stage_wt(W, Wt, t);
  const int row0 = blockIdx.x * 64;
  #pragma unroll
  for (int i = 0; i < 4; ++i) {
    int idx = t + 256 * i;        // 1024 items: row, 16B col group
    int r = idx >> 4, c4 = idx & 15;
    int gr = row0 + r;
    float4 v = {0.f, 0.f, 0.f, 0.f};
    float s = 0.f;
    if (gr < n) {
      v = *(const float4*)&A[(size_t)gr * NF + c4 * 4];
      s = so[gr];
    }
    ushort4 o;
    o.x = f2bf(v.x * s); o.y = f2bf(v.y * s);
    o.z = f2bf(v.z * s); o.w = f2bf(v.w * s);
    *(ushort4*)&Ab[r * 72 + c4 * 4] = o;
  }
  __syncthreads();
  mfma_gemm_core(Ab, Wt, H, row0, n, t);
}

// Layer 2: h2 = bf16(t @ W2), bf16 input.
__global__ __launch_bounds__(256) void gemm2_kernel(
    const unsigned short* __restrict__ Tb, const float* __restrict__ W,
    unsigned short* __restrict__ H, int n) {
  __shared__ __align__(16) unsigned short Ab[64 * 72];
  __shared__ __align__(16) unsigned short Wt[64 * 72];
  const int t = threadIdx.x;
  stage_wt(W, Wt, t);
  const int row0 = blockIdx.x * 64;
  #pragma unroll
  for (int i = 0; i < 4; ++i) {
    int idx = t + 256 * i;
    int r = idx >> 4, c4 = idx & 15;
    int gr = row0 + r;
    ushort4 v = {0, 0, 0, 0};
    if (gr < n) v = *(const ushort4*)&Tb[(size_t)gr * NF + c4 * 4];
    *(ushort4*)&Ab[r * 72 + c4 * 4] = v;
  }
  __syncthreads();
  mfma_gemm_core(Ab, Wt, H, row0, n, t);
}

// ---------------------------------------------------------------------------
// Gather/accumulate (one wave per node, bf16 rows = 128 B, 8 rows per VMEM
// instruction; butterfly leaves the full row sum in every lane:
// features (lane&7)*8 .. +7 in acc[0..7]).
__device__ __forceinline__ void gather_sum(
    const unsigned short* __restrict__ H, const unsigned short* __restrict__ srcs,
    int beg, int end, int g, int c, float* acc) {
  const float4* Hv = (const float4*)H;
  int e = beg;
  for (; e + 16 <= end; e += 16) {
    int ia = srcs[e + g];
    int ib = srcs[e + 8 + g];
    float4 va = Hv[(size_t)ia * 8 + c];
    float4 vb = Hv[(size_t)ib * 8 + c];
    const unsigned int* pa = (const unsigned int*)&va;
    const unsigned int* pb = (const unsigned int*)&vb;
    #pragma unroll
    for (int k = 0; k < 4; ++k) {
      acc[2 * k]     += __uint_as_float(pa[k] << 16) + __uint_as_float(pb[k] << 16);
      acc[2 * k + 1] += __uint_as_float(pa[k] & 0xffff0000u) + __uint_as_float(pb[k] & 0xffff0000u);
    }
  }
  if (e + 8 <= end) {
    int ia = srcs[e + g];
    float4 va = Hv[(size_t)ia * 8 + c];
    const unsigned int* pa = (const unsigned int*)&va;
    #pragma unroll
    for (int k = 0; k < 4; ++k) {
      acc[2 * k]     += __uint_as_float(pa[k] << 16);
      acc[2 * k + 1] += __uint_as_float(pa[k] & 0xffff0000u);
    }
    e += 8;
  }
  if (e < end) {
    int idx = (e + g < end) ? (e + g) : (end - 1);
    float m = (e + g < end) ? 1.f : 0.f;
    int ia = srcs[idx];
    float4 va = Hv[(size_t)ia * 8 + c];
    const unsigned int* pa = (const unsigned int*)&va;
    #pragma unroll
    for (int k = 0; k < 4; ++k) {
      acc[2 * k]     += m * __uint_as_float(pa[k] << 16);
      acc[2 * k + 1] += m * __uint_as_float(pa[k] & 0xffff0000u);
    }
  }
  #pragma unroll
  for (int d = 8; d <= 32; d <<= 1) {
    #pragma unroll
    for (int k = 0; k < 8; ++k) acc[k] += __shfl_xor(acc[k], d);
  }
}

// Layer-1 aggregation: t = bf16(relu(segsum(h1)*si + b1) * so).
__global__ __launch_bounds__(256) void agg1_kernel(
    const unsigned short* __restrict__ H1, const int* __restrict__ row_start,
    const unsigned short* __restrict__ srcs, const float* __restrict__ si,
    const float* __restrict__ so, const float* __restrict__ b1,
    unsigned short* __restrict__ T, int n) {
  int node = blockIdx.x * 4 + (threadIdx.x >> 6);
  if (node >= n) return;
  const int lane = threadIdx.x & 63;
  const int g = lane >> 3;
  const int c = lane & 7;
  float acc[8] = {0, 0, 0, 0, 0, 0, 0, 0};
  gather_sum(H1, srcs, row_start[node], row_start[node + 1], g, c, acc);
  if (g == 0) {
    const float sin = si[node];
    const float son = so[node];
    ushort4 o0, o1;
    float v;
    v = fmaxf(fmaf(acc[0], sin, b1[c * 8 + 0]), 0.f) * son; o0.x = f2bf(v);
    v = fmaxf(fmaf(acc[1], sin, b1[c * 8 + 1]), 0.f) * son; o0.y = f2bf(v);
    v = fmaxf(fmaf(acc[2], sin, b1[c * 8 + 2]), 0.f) * son; o0.z = f2bf(v);
    v = fmaxf(fmaf(acc[3], sin, b1[c * 8 + 3]), 0.f) * son; o0.w = f2bf(v);
    v = fmaxf(fmaf(acc[4], sin, b1[c * 8 + 4]), 0.f) * son; o1.x = f2bf(v);
    v = fmaxf(fmaf(acc[5], sin, b1[c * 8 + 5]), 0.f) * son; o1.y = f2bf(v);
    v = fmaxf(fmaf(acc[6], sin, b1[c * 8 + 6]), 0.f) * son; o1.z = f2bf(v);
    v = fmaxf(fmaf(acc[7], sin, b1[c * 8 + 7]), 0.f) * son; o1.w = f2bf(v);
    *(ushort4*)&T[(size_t)node * NF + c * 8]     = o0;
    *(ushort4*)&T[(size_t)node * NF + c * 8 + 4] = o1;
  }
}

// Layer-2 aggregation: out = segsum(h2)*si + b2 (f32).
__global__ __launch_bounds__(256) void agg2_kernel(
    const unsigned short* __restrict__ H2, const int* __restrict__ row_start,
    const unsigned short* __restrict__ srcs, const float* __restrict__ si,
    const float* __restrict__ b2, float* __restrict__ out, int n) {
  int node = blockIdx.x * 4 + (threadIdx.x >> 6);
  if (node >= n) return;
  const int lane = threadIdx.x & 63;
  const int g = lane >> 3;
  const int c = lane & 7;
  float acc[8] = {0, 0, 0, 0, 0, 0, 0, 0};
  gather_sum(H2, srcs, row_start[node], row_start[node + 1], g, c, acc);
  if (g == 0) {
    const float sin = si[node];
    const float4 b4a = *(const float4*)&b2[c * 8];
    const float4 b4b = *(const float4*)&b2[c * 8 + 4];
    float4 r0, r1;
    r0.x = fmaf(acc[0], sin, b4a.x);
    r0.y = fmaf(acc[1], sin, b4a.y);
    r0.z = fmaf(acc[2], sin, b4a.z);
    r0.w = fmaf(acc[3], sin, b4a.w);
    r1.x = fmaf(acc[4], sin, b4b.x);
    r1.y = fmaf(acc[5], sin, b4b.y);
    r1.z = fmaf(acc[6], sin, b4b.z);
    r1.w = fmaf(acc[7], sin, b4b.w);
    *(float4*)&out[(size_t)node * NF + c * 8]     = r0;
    *(float4*)&out[(size_t)node * NF + c * 8 + 4] = r1;
  }
}

// ---------------------------------------------------------------------------
extern "C" void kernel_launch(void* const* d_in, const int* in_sizes, int n_in,
                              void* d_out, int out_size, void* d_ws, size_t ws_size,
                              hipStream_t stream) {
  const float* x  = (const float*)d_in[0];
  const float* W1 = (const float*)d_in[1];
  const float* b1 = (const float*)d_in[2];
  const float* W2 = (const float*)d_in[3];
  const float* b2 = (const float*)d_in[4];
  const int* src  = (const int*)d_in[5];
  const int* dst  = (const int*)d_in[6];
  float* out = (float*)d_out;

  const int N = in_sizes[0] / NF;   // 50000 (< 65536 for ushort ids)
  const int E = in_sizes[5];        // 800000
  const int NB = (N + 255) / 256;   // 196 <= 256
  const int R  = (N + RANGE - 1) / RANGE;       // 7
  const int CH = (((E + BC - 1) / BC) + 3) & ~3; // chunk, 4-aligned (12500)

  // Workspace (~30 MB). base (BC*N*4 = 12.8 MB) aliases [tb, G_out]: both are
  // dead/unwritten during scan3->place; tb is written by agg1 (after place)
  // and G_out is dead after colscan. h1 is separate (written by the fused
  // place+gemm1 kernel while place reads base).
  char* ws = (char*)d_ws;
  size_t p = 0;
  auto alloc = [&](size_t bytes) -> void* {
    void* r = ws + p;
    p = (p + bytes + 255) & ~(size_t)255;
    return r;
  };
  int*   deg_out_i  = (int*)  alloc((size_t)N * 4);
  int*   deg_in_i   = (int*)  alloc((size_t)N * 4);
  float* so         = (float*)alloc((size_t)N * 4);
  float* si         = (float*)alloc((size_t)N * 4);
  int*   row_start  = (int*)  alloc((size_t)(N + 1) * 4);
  int*   bsum       = (int*)  alloc((size_t)NB * 4);
  int*   lscan      = (int*)  alloc((size_t)N * 4);
  unsigned short* sorted_u16 = (unsigned short*)alloc((size_t)E * 2);
  unsigned char*  rank  = (unsigned char*)alloc((size_t)E);             // 0.8 MB
  unsigned short* h1    = (unsigned short*)alloc((size_t)N * NF * 2);   // 6.4 MB
  unsigned short* G_in  = (unsigned short*)alloc((size_t)BC * N * 2);   // 6.4 MB
  unsigned short* tb    = (unsigned short*)alloc((size_t)N * NF * 2);   // 6.4 MB
  unsigned short* G_out = (unsigned short*)alloc((size_t)BC * N * 2);   // 6.4 MB
  int* base = (int*)tb;        // 12.8 MB alias over [tb, G_out]
  unsigned short* h2 = h1;     // h1 dead once agg1 completes; gemm2 runs after

  // 1. per-(range,chunk) histograms for both endpoints (+ rank capture)
  hist_kernel<<<2 * R * BC, 256, 0, stream>>>(src, dst, G_out, G_in, rank,
                                              N, E, R, CH);

  // 2. fused column-scan (per-chunk bases + degrees) + block scan
  colscan_scan1_kernel<<<NB, 256, 0, stream>>>(G_in, G_out, deg_in_i, deg_out_i,
                                               lscan, bsum, N);

  // 3. row_start + so/si + base matrix
  scan3_kernel<<<NB, 256, 0, stream>>>(lscan, bsum, deg_out_i, deg_in_i,
                                       G_in, base, row_start, so, si, N, E);

  const int ggrid = (N + 63) / 64;
  const int pgrid = (E + 255) / 256;
  const int agrid = (N + 3) / 4;

  // 4. fused: layer-1 MFMA GEMM (h1) + parallel atomic-free placement
  place_gemm1_kernel<<<ggrid + pgrid, 256, 0, stream>>>(
      x, so, W1, h1, N, ggrid, src, dst, rank, base, sorted_u16, E, CH);

  // 5. t = bf16(relu(segsum(h1)*si + b1) * so)
  agg1_kernel<<<agrid, 256, 0, stream>>>(h1, row_start, sorted_u16, si, so, b1, tb, N);

  // 6. h2 = bf16(t @ W2)   [MFMA]
  gemm2_kernel<<<ggrid, 256, 0, stream>>>(tb, W2, h2, N);

  // 7. out = segsum(h2)*si + b2
  agg2_kernel<<<agrid, 256, 0, stream>>>(h2, row_start, sorted_u16, si, b2, out, N);
}